// Round 8
// baseline (354.212 us; speedup 1.0000x reference)
//
#include <hip/hip_runtime.h>
#include <math.h>

// ---------------------------------------------------------------------------
// Restormer block, B=1 DIM=3 NC=512 HEADS=2 -> CT=768, NT=32, HID=6. f32 I/O.
//
// conv3x3 (+) MLP-stage1 collapsed through G = row-correlations of x with w1
// columns. R8: k_mlp back to 4-way h-split (R7's 8-way doubled atomic HBM
// write traffic, 37->76MB); k_qk/k_av LDS staging remapped so column-scatter
// stores are 2-lanes/bank (was 8-way conflict, 4.1M cycles); k_soft 4 rows
// per 256-thr block.
// ---------------------------------------------------------------------------

__device__ __forceinline__ float sigm(float s) {
    return __builtin_amdgcn_rcpf(1.f + __expf(-s));
}

// ---- f32 workspace layout (element offsets) -------------------------------
static constexpr int OFF_G   = 0;         // [3v][515 rows][3ci][32n][4]; rows 0,513,514 zero pad
static constexpr int GSTRIDE = 197760;    // 515*384
static constexpr int OFF_S1  = 593280;    // [3v][32] column sums of w1
static constexpr int OFF_QKV = 593408;    // [3v][4head][768c][256s]
static constexpr int OFF_SC  = 2952704;   // [4head][768][768]; ALSO pre-sigmoid PS [3v][768c][32o][32n]
static constexpr int OFF_ATT = 5312000;   // [4head][768][256] == (3,512,512) flat
// total 6098432 floats = 24.4 MB

// ---------------------------------------------------------------------------
// k_prep: zero G pad rows; S1[v][n] = sum_u w1v[u][n]; zero PS accumulator.
// ---------------------------------------------------------------------------
__global__ __launch_bounds__(256) void k_prep(const float* __restrict__ qw1,
                                              const float* __restrict__ kw1,
                                              const float* __restrict__ vw1,
                                              float* __restrict__ ws) {
    int i = blockIdx.x * 256 + threadIdx.x;
    if (i < 3456) {                        // zero G pad rows 0,513,514 per v
        int v = i / 1152, rr = (i % 1152) / 384, col = i % 384;
        int row = (rr == 0) ? 0 : (512 + rr);
        ws[OFF_G + v * GSTRIDE + row * 384 + col] = 0.f;
    } else if (i >= 3584 && i < 9728) {    // S1: 96 waves, shuffle-reduce
        int j = i - 3584;
        int w = j >> 6, lane = j & 63;
        int v = w >> 5, n = w & 31;
        const float* w1p = (v == 0) ? qw1 : ((v == 1) ? kw1 : vw1);
        float s = 0.f;
#pragma unroll
        for (int k = 0; k < 8; k++) s += w1p[(lane + 64 * k) * 32 + n];
#pragma unroll
        for (int off = 32; off > 0; off >>= 1) s += __shfl_xor(s, off);
        if (lane == 0) ws[OFF_S1 + w] = s;
    } else if (i >= 9728 && i < 9728 + 2359296) {
        ws[OFF_SC + (i - 9728)] = 0.f;     // PS init
    }
}

// ---------------------------------------------------------------------------
// k_corr: G[v][h+1][ci][n][dx] = sum_u x[ci][h][u] * w1v[u+1-dx][n]
// grid (64 hblk, 3 ci, 3 v), block 256 = 8 rows x 32 n. float4 G stores.
// ---------------------------------------------------------------------------
__global__ __launch_bounds__(256) void k_corr(const float* __restrict__ x,
                                              const float* __restrict__ qw1,
                                              const float* __restrict__ kw1,
                                              const float* __restrict__ vw1,
                                              float* __restrict__ ws) {
    const int h0 = blockIdx.x * 8, ci = blockIdx.y, v = blockIdx.z;
    const int tid = threadIdx.x;
    __shared__ __align__(16) float ws1t[32 * 516];

    const float* w1f = (v == 0) ? qw1 : ((v == 1) ? kw1 : vw1);
    for (int i = tid; i < 4096; i += 256) {       // transpose-stage w1
        int n_ = i & 31, u = (i >> 5) * 4;
        float a = w1f[(u + 0) * 32 + n_];
        float b = w1f[(u + 1) * 32 + n_];
        float c = w1f[(u + 2) * 32 + n_];
        float d = w1f[(u + 3) * 32 + n_];
        *(float4*)&ws1t[n_ * 516 + u] = make_float4(a, b, c, d);
    }
    if (tid < 32) *(float4*)&ws1t[tid * 516 + 512] = make_float4(0.f, 0.f, 0.f, 0.f);
    __syncthreads();

    const int hp = tid >> 5, n = tid & 31;
    const float* xrow = x + ci * 262144 + (h0 + hp) * 512;
    float a0 = 0.f, a1 = 0.f, a2 = 0.f, pq = 0.f;
    float4 cq = *(float4*)&ws1t[n * 516];
#pragma unroll 4
    for (int k = 0; k < 128; k++) {
        float4 nq = *(float4*)&ws1t[n * 516 + 4 * k + 4];
        float4 x4 = *(const float4*)&xrow[4 * k];
        a1 = fmaf(x4.x, cq.x, a1); a1 = fmaf(x4.y, cq.y, a1);
        a1 = fmaf(x4.z, cq.z, a1); a1 = fmaf(x4.w, cq.w, a1);
        a0 = fmaf(x4.x, cq.y, a0); a0 = fmaf(x4.y, cq.z, a0);
        a0 = fmaf(x4.z, cq.w, a0); a0 = fmaf(x4.w, nq.x, a0);
        a2 = fmaf(x4.x, pq,   a2); a2 = fmaf(x4.y, cq.x, a2);
        a2 = fmaf(x4.z, cq.y, a2); a2 = fmaf(x4.w, cq.z, a2);
        pq = cq.w; cq = nq;
    }
    float* g = ws + OFF_G + v * GSTRIDE + (h0 + hp + 1) * 384 + ci * 128 + n * 4;
    *(float4*)g = make_float4(a0, a1, a2, 0.f);
}

// ---------------------------------------------------------------------------
// k_mlp: per (v, c): y1[h,n] = sigm(b1 + cb*S1 + 27-tap gather from G),
// stage-2 acc[o] += y1*w2[h][o] over a 128-h chunk, atomicAdd into PS.
// grid (96 cblk, 4 hchunk, 3 v), block 256 (8 channels x 32 n). No LDS.
// Rolling 4-slot tap rows, each refill = 3 float4 loads. w2 rows scalar-
// prefetched one ahead.
// ---------------------------------------------------------------------------
struct MlpPtrs {
    const float* b1[3];
    const float* w2[3];
    const float* b2[3];
};

__device__ __forceinline__ void rd32(float w[32], const float* __restrict__ p) {
#pragma unroll
    for (int o = 0; o < 32; o++) w[o] = p[o];
}

__global__ __launch_bounds__(256, 4) void k_mlp(const float* __restrict__ cwp,
                                                const float* __restrict__ cbp,
                                                MlpPtrs mp, float* __restrict__ ws) {
    const int cb = blockIdx.x, hc = blockIdx.y, v = blockIdx.z;
    const int tid = threadIdx.x, cl = tid >> 5, n = tid & 31;
    const int c = cb * 8 + cl;
    const int h0 = hc * 128;

    const float* gv  = ws + OFF_G + v * GSTRIDE;
    const float* w2p = mp.w2[v];

    float cwr[3][9];                                // [dy][ci*3+dx]
#pragma unroll
    for (int dy = 0; dy < 3; dy++)
#pragma unroll
        for (int q = 0; q < 9; q++)
            cwr[dy][q] = cwp[c * 27 + (q / 3) * 9 + dy * 3 + (q % 3)];
    const float base = mp.b1[v][n] + cbp[c] * ws[OFF_S1 + v * 32 + n];

    float acc[32];
#pragma unroll
    for (int o = 0; o < 32; o++) acc[o] = 0.f;

    float R[4][12];                                 // [slot][ci*4+dx]
    const float* rp = gv + h0 * 384 + n * 4;        // this lane's tap base
#pragma unroll
    for (int r = 0; r < 4; r++)
#pragma unroll
        for (int ci = 0; ci < 3; ci++)
            *(float4*)&R[r][ci * 4] = *(const float4*)(rp + r * 384 + ci * 128);
    rp += 4 * 384;                                  // next row to fetch: h0+4

    float wbuf[2][32];
    rd32(wbuf[0], w2p + h0 * 32);

    for (int hb = 0; hb < 32; hb++) {
#pragma unroll
        for (int k = 0; k < 4; k++) {
            const int h = h0 + hb * 4 + k;
            // prefetch next w2 row (wave-uniform -> scalar loads)
            int hn = h + 1; if (hn > 511) hn = 511;
            rd32(wbuf[(k + 1) & 1], w2p + hn * 32);
            // taps: rows h,h+1,h+2 live in slots k, k+1, k+2 (mod 4)
            float s0 = base, s1 = 0.f, s2 = 0.f;
#pragma unroll
            for (int q = 0; q < 9; q++) {
                int qi = (q / 3) * 4 + (q % 3);
                s0 = fmaf(cwr[0][q], R[(k + 0) & 3][qi], s0);
                s1 = fmaf(cwr[1][q], R[(k + 1) & 3][qi], s1);
                s2 = fmaf(cwr[2][q], R[(k + 2) & 3][qi], s2);
            }
            // refill freed slot k with G-row h+4: 3x dwordx4
#pragma unroll
            for (int ci = 0; ci < 3; ci++)
                *(float4*)&R[k & 3][ci * 4] = *(const float4*)(rp + k * 384 + ci * 128);
            float y = sigm((s0 + s1) + s2);
#pragma unroll
            for (int o = 0; o < 32; o++) acc[o] = fmaf(y, wbuf[k & 1][o], acc[o]);
        }
        rp += 4 * 384;
    }

    float* ps = ws + OFF_SC + ((v * 768 + c) * 32) * 32;   // [o][n]
#pragma unroll
    for (int o = 0; o < 32; o++) atomicAdd(&ps[o * 32 + n], acc[o]);
}

// ---------------------------------------------------------------------------
// k_mlp2: PS -> +b2 -> sigmoid -> split-heads scatter into QKV.
// Output-indexed: coalesced QKV writes, permutation on the read side.
// ---------------------------------------------------------------------------
__global__ __launch_bounds__(256) void k_mlp2(MlpPtrs mp, float* __restrict__ ws) {
    int i = blockIdx.x * 256 + threadIdx.x;       // over 3*4*768*256
    if (i >= 2359296) return;
    int sidx = i & 255;
    int r = i >> 8;                                // v*3072 + head*768 + c
    int c = r % 768;
    int head = (r / 768) & 3;
    int v = r / 3072;
    int o = ((sidx >> 4) << 1) | (head >> 1);
    int n = ((sidx & 15) << 1) | (head & 1);
    float m = sigm(ws[OFF_SC + ((v * 768 + c) * 32 + o) * 32 + n] + mp.b2[v][o]);
    ws[OFF_QKV + v * 786432 + head * 196608 + c * 256 + sidx] = m;
}

// ---------------------------------------------------------------------------
// k_qk: scores[head] = temp[head] * Q @ K^T   (768x768, K=256)
// 64x64 tiles, 4x4 micro-tile, LDS [k][row] layout. Staging remapped
// (r = tid&15, k4 = (tid>>4)*4): scatter stores land 2 lanes/bank (free).
// ---------------------------------------------------------------------------
__global__ __launch_bounds__(256) void k_qk(const float* __restrict__ tempr,
                                            float* __restrict__ ws) {
    const int i0 = blockIdx.x * 64, j0 = blockIdx.y * 64, head = blockIdx.z;
    const float* Q = ws + OFF_QKV + head * 196608;             // v=0
    const float* K = ws + OFF_QKV + 786432 + head * 196608;    // v=1
    float* S = ws + OFF_SC + head * 589824;
    const float temp = tempr[head];
    __shared__ __align__(16) float Qs[64][68];
    __shared__ __align__(16) float Ks[64][68];
    const int tid = threadIdx.x, ty = tid >> 4, tx = tid & 15;
    const int sr = tid & 15, sk4 = (tid >> 4) * 4;   // staging map
    float acc[4][4] = {};

    for (int kc = 0; kc < 256; kc += 64) {
        __syncthreads();
#pragma unroll
        for (int it = 0; it < 4; it++) {
            int r = sr + 16 * it;
            float4 q = *(const float4*)&Q[(i0 + r) * 256 + kc + sk4];
            Qs[sk4 + 0][r] = q.x; Qs[sk4 + 1][r] = q.y;
            Qs[sk4 + 2][r] = q.z; Qs[sk4 + 3][r] = q.w;
            float4 k = *(const float4*)&K[(j0 + r) * 256 + kc + sk4];
            Ks[sk4 + 0][r] = k.x; Ks[sk4 + 1][r] = k.y;
            Ks[sk4 + 2][r] = k.z; Ks[sk4 + 3][r] = k.w;
        }
        __syncthreads();
#pragma unroll
        for (int k = 0; k < 64; k++) {
            float4 a = *(float4*)&Qs[k][ty * 4];
            float4 b = *(float4*)&Ks[k][tx * 4];
            float av[4] = {a.x, a.y, a.z, a.w}, bv[4] = {b.x, b.y, b.z, b.w};
#pragma unroll
            for (int e = 0; e < 4; e++)
#pragma unroll
                for (int f = 0; f < 4; f++) acc[e][f] = fmaf(av[e], bv[f], acc[e][f]);
        }
    }
#pragma unroll
    for (int e = 0; e < 4; e++) {
        float4 r = make_float4(acc[e][0] * temp, acc[e][1] * temp,
                               acc[e][2] * temp, acc[e][3] * temp);
        *(float4*)&S[(i0 + ty * 4 + e) * 768 + j0 + tx * 4] = r;
    }
}

// ---------------------------------------------------------------------------
// k_soft: row softmax over 768. 256-thr blocks, 4 rows/block (one per wave).
// ---------------------------------------------------------------------------
__global__ __launch_bounds__(256) void k_soft(float* __restrict__ ws) {
    float* row = ws + OFF_SC + ((size_t)blockIdx.x * 4 + (threadIdx.x >> 6)) * 768;
    const int t = threadIdx.x & 63;
    float4 v0 = *(float4*)&row[t * 12];
    float4 v1 = *(float4*)&row[t * 12 + 4];
    float4 v2 = *(float4*)&row[t * 12 + 8];
    float m0 = fmaxf(fmaxf(v0.x, v0.y), fmaxf(v0.z, v0.w));
    float m1 = fmaxf(fmaxf(v1.x, v1.y), fmaxf(v1.z, v1.w));
    float m2 = fmaxf(fmaxf(v2.x, v2.y), fmaxf(v2.z, v2.w));
    float m = fmaxf(fmaxf(m0, m1), m2);
#pragma unroll
    for (int off = 32; off > 0; off >>= 1) m = fmaxf(m, __shfl_xor(m, off));
    v0.x = __expf(v0.x - m); v0.y = __expf(v0.y - m); v0.z = __expf(v0.z - m); v0.w = __expf(v0.w - m);
    v1.x = __expf(v1.x - m); v1.y = __expf(v1.y - m); v1.z = __expf(v1.z - m); v1.w = __expf(v1.w - m);
    v2.x = __expf(v2.x - m); v2.y = __expf(v2.y - m); v2.z = __expf(v2.z - m); v2.w = __expf(v2.w - m);
    float s = v0.x + v0.y + v0.z + v0.w + v1.x + v1.y + v1.z + v1.w + v2.x + v2.y + v2.z + v2.w;
#pragma unroll
    for (int off = 32; off > 0; off >>= 1) s += __shfl_xor(s, off);
    float inv = __builtin_amdgcn_rcpf(s);
    v0.x *= inv; v0.y *= inv; v0.z *= inv; v0.w *= inv;
    v1.x *= inv; v1.y *= inv; v1.z *= inv; v1.w *= inv;
    v2.x *= inv; v2.y *= inv; v2.z *= inv; v2.w *= inv;
    *(float4*)&row[t * 12]     = v0;
    *(float4*)&row[t * 12 + 4] = v1;
    *(float4*)&row[t * 12 + 8] = v2;
}

// ---------------------------------------------------------------------------
// k_av: ATT[head] = attn @ V  (768x256, K=768). 32x64 tiles (384 blocks),
// 2x4 micro-tile. As staging remapped (r = tid&31, k4 = (tid>>5)*4 + 32*it)
// -> scatter stores 2 lanes/bank (free).
// ---------------------------------------------------------------------------
__global__ __launch_bounds__(256) void k_av(float* __restrict__ ws) {
    const int i0 = blockIdx.x * 32, s0 = blockIdx.y * 64, head = blockIdx.z;
    const float* A = ws + OFF_SC + head * 589824;
    const float* V = ws + OFF_QKV + 2 * 786432 + head * 196608;
    float* O = ws + OFF_ATT + head * 196608;
    __shared__ __align__(16) float As[64][34];
    __shared__ __align__(16) float Bs[64][68];
    const int tid = threadIdx.x, ty = tid >> 4, tx = tid & 15;
    const int sr = tid & 31, sq = tid >> 5;          // staging map
    float acc[2][4] = {};

    for (int dc = 0; dc < 768; dc += 64) {
        __syncthreads();
#pragma unroll
        for (int it = 0; it < 2; it++) {
            int k4 = sq * 4 + 32 * it;
            float4 a = *(const float4*)&A[(i0 + sr) * 768 + dc + k4];
            As[k4 + 0][sr] = a.x; As[k4 + 1][sr] = a.y;
            As[k4 + 2][sr] = a.z; As[k4 + 3][sr] = a.w;
        }
        for (int idx = tid; idx < 1024; idx += 256) {
            int r = idx >> 4, k4 = (idx & 15) * 4;
            *(float4*)&Bs[r][k4] = *(const float4*)&V[(dc + r) * 256 + s0 + k4];
        }
        __syncthreads();
#pragma unroll
        for (int k = 0; k < 64; k++) {
            float a0 = As[k][ty * 2], a1 = As[k][ty * 2 + 1];
            float4 b = *(float4*)&Bs[k][tx * 4];
            acc[0][0] = fmaf(a0, b.x, acc[0][0]); acc[0][1] = fmaf(a0, b.y, acc[0][1]);
            acc[0][2] = fmaf(a0, b.z, acc[0][2]); acc[0][3] = fmaf(a0, b.w, acc[0][3]);
            acc[1][0] = fmaf(a1, b.x, acc[1][0]); acc[1][1] = fmaf(a1, b.y, acc[1][1]);
            acc[1][2] = fmaf(a1, b.z, acc[1][2]); acc[1][3] = fmaf(a1, b.w, acc[1][3]);
        }
    }
#pragma unroll
    for (int e = 0; e < 2; e++) {
        float4 r = make_float4(acc[e][0], acc[e][1], acc[e][2], acc[e][3]);
        *(float4*)&O[(i0 + ty * 2 + e) * 256 + s0 + tx * 4] = r;
    }
}

// ---------------------------------------------------------------------------
// k_ffn: fused pointwise(3->12) + dwconv3x3 + gelu-gate + pointwise(6->3)
// + residual, f32 store. 32x16 pixel tiles (512 blocks), 34x18 halo in LDS.
// ---------------------------------------------------------------------------
struct FfnPtrs { const float* p[6]; };  // pi_w, pi_b, dw_w, dw_b, po_w, po_b

__global__ __launch_bounds__(256) void k_ffn(const float* __restrict__ ws,
                                             const float* __restrict__ x,
                                             FfnPtrs fp,
                                             float* __restrict__ out) {
    const int x0 = blockIdx.x * 32, y0 = blockIdx.y * 16;
    __shared__ float wsm[192];
    __shared__ float p[12][612];
    const int tid = threadIdx.x;
    if (tid < 36)       wsm[tid] = fp.p[0][tid];          // pi_w (12,3)
    else if (tid < 48)  wsm[tid] = fp.p[1][tid - 36];     // pi_b (12)
    else if (tid < 156) wsm[tid] = fp.p[2][tid - 48];     // dw_w (12,9)
    else if (tid < 168) wsm[tid] = fp.p[3][tid - 156];    // dw_b (12)
    else if (tid < 186) wsm[tid] = fp.p[4][tid - 168];    // po_w (3,6)
    else if (tid < 189) wsm[tid] = fp.p[5][tid - 186];    // po_b (3)
    __syncthreads();

    const float* A = ws + OFF_ATT;
    for (int i = tid; i < 612; i += 256) {
        int py = i / 34, px = i % 34;
        int gy = y0 + py - 1, gx = x0 + px - 1;
        bool in = ((unsigned)gy < 512u) && ((unsigned)gx < 512u);
        float a0 = 0.f, a1 = 0.f, a2 = 0.f;
        if (in) {
            int b = gy * 512 + gx;
            a0 = A[b]; a1 = A[262144 + b]; a2 = A[524288 + b];
        }
#pragma unroll
        for (int j = 0; j < 12; j++) {
            float t = in ? (wsm[36 + j] + wsm[j * 3] * a0 + wsm[j * 3 + 1] * a1
                            + wsm[j * 3 + 2] * a2)
                         : 0.f;
            p[j][i] = t;
        }
    }
    __syncthreads();

#pragma unroll
    for (int it = 0; it < 2; it++) {
        int pl = tid + it * 256;
        int ly = pl >> 5, lx = pl & 31;
        float z[12];
#pragma unroll
        for (int j = 0; j < 12; j++) {
            const float* dw = &wsm[48 + j * 9];
            const float* pr = &p[j][ly * 34 + lx];
            z[j] = wsm[156 + j]
                 + dw[0] * pr[0]  + dw[1] * pr[1]  + dw[2] * pr[2]
                 + dw[3] * pr[34] + dw[4] * pr[35] + dw[5] * pr[36]
                 + dw[6] * pr[68] + dw[7] * pr[69] + dw[8] * pr[70];
        }
        float g[6];
#pragma unroll
        for (int j = 0; j < 6; j++) {
            float xx = z[j];
            g[j] = 0.5f * xx * (1.f + erff(xx * 0.70710678118f)) * z[6 + j];
        }
        int b = (y0 + ly) * 512 + (x0 + lx);
#pragma unroll
        for (int co = 0; co < 3; co++) {
            float r = wsm[186 + co];
#pragma unroll
            for (int j = 0; j < 6; j++) r = fmaf(wsm[168 + co * 6 + j], g[j], r);
            r += x[co * 262144 + b];             // residual
            out[co * 262144 + b] = r;
        }
    }
}

// ---------------------------------------------------------------------------
extern "C" void kernel_launch(void* const* d_in, const int* in_sizes, int n_in,
                              void* d_out, int out_size, void* d_ws, size_t ws_size,
                              hipStream_t stream) {
    float* ws = (float*)d_ws;
    float* out = (float*)d_out;
    const float* x   = (const float*)d_in[0];
    const float* cw  = (const float*)d_in[1];
    const float* cb  = (const float*)d_in[2];
    const float* qw1 = (const float*)d_in[3];
    const float* kw1 = (const float*)d_in[7];
    const float* vw1 = (const float*)d_in[11];
    const float* temp= (const float*)d_in[15];

    MlpPtrs mp;
    mp.b1[0] = (const float*)d_in[4];  mp.w2[0] = (const float*)d_in[5];  mp.b2[0] = (const float*)d_in[6];
    mp.b1[1] = (const float*)d_in[8];  mp.w2[1] = (const float*)d_in[9];  mp.b2[1] = (const float*)d_in[10];
    mp.b1[2] = (const float*)d_in[12]; mp.w2[2] = (const float*)d_in[13]; mp.b2[2] = (const float*)d_in[14];

    FfnPtrs fp;
    for (int i = 0; i < 6; i++) fp.p[i] = (const float*)d_in[16 + i];

    k_prep<<<9254, 256, 0, stream>>>(qw1, kw1, vw1, ws);
    k_corr<<<dim3(64, 3, 3), 256, 0, stream>>>(x, qw1, kw1, vw1, ws);
    k_mlp <<<dim3(96, 4, 3), 256, 0, stream>>>(cw, cb, mp, ws);
    k_mlp2<<<9216, 256, 0, stream>>>(mp, ws);
    k_qk  <<<dim3(12, 12, 4), 256, 0, stream>>>(temp, ws);
    k_soft<<<768, 256, 0, stream>>>(ws);
    k_av  <<<dim3(24, 4, 4), 256, 0, stream>>>(ws);
    k_ffn <<<dim3(16, 32), 256, 0, stream>>>(ws, x, fp, out);
}

// Round 9
// 298.691 us; speedup vs baseline: 1.1859x; 1.1859x over previous
//
#include <hip/hip_runtime.h>
#include <math.h>

// ---------------------------------------------------------------------------
// Restormer block, B=1 DIM=3 NC=512 HEADS=2 -> CT=768, NT=32, HID=6. f32 I/O.
//
// conv3x3 (+) MLP-stage1 collapsed through G = row-correlations of x with w1
// columns. R9: k_mlp stage-2 moved to MFMA — one wave per (v,c) computes the
// 32x32x512 GEMM acc[n][o] += y1[h,n]*w2[h,o] via mfma_f32_32x32x16_bf16
// (A-frag: n=lane&31, h=8*(lane>>5)+j; C/D: col=o, row=(reg&3)+8*(reg>>2)
// +4*(lane>>5)). Epilogue +b2/sigmoid/split-heads writes QKV directly: PS
// buffer, its zeroing, 39MB of atomics, and k_mlp2 are all eliminated.
// ---------------------------------------------------------------------------

__device__ __forceinline__ float sigm(float s) {
    return __builtin_amdgcn_rcpf(1.f + __expf(-s));
}

using bf16x8 = __attribute__((ext_vector_type(8))) short;   // 8 bf16 (4 VGPRs)
using f32x16 = __attribute__((ext_vector_type(16))) float;

__device__ __forceinline__ short f2bf(float f) {
    union { __bf16 h; short s; } u;
    u.h = (__bf16)f;                    // HW cvt, RNE
    return u.s;
}

// ---- f32 workspace layout (element offsets) -------------------------------
static constexpr int OFF_G   = 0;         // [3v][515 rows][3ci][32n][4]; rows 0,513,514 zero pad
static constexpr int GSTRIDE = 197760;    // 515*384
static constexpr int OFF_S1  = 593280;    // [3v][32] column sums of w1
static constexpr int OFF_QKV = 593408;    // [3v][4head][768c][256s]
static constexpr int OFF_SC  = 2952704;   // [4head][768][768] scores
static constexpr int OFF_ATT = 5312000;   // [4head][768][256] == (3,512,512) flat
// total 6098432 floats = 24.4 MB

// ---------------------------------------------------------------------------
// k_prep: zero G pad rows; S1[v][n] = sum_u w1v[u][n]. (No PS any more.)
// ---------------------------------------------------------------------------
__global__ __launch_bounds__(256) void k_prep(const float* __restrict__ qw1,
                                              const float* __restrict__ kw1,
                                              const float* __restrict__ vw1,
                                              float* __restrict__ ws) {
    int i = blockIdx.x * 256 + threadIdx.x;
    if (i < 3456) {                        // zero G pad rows 0,513,514 per v
        int v = i / 1152, rr = (i % 1152) / 384, col = i % 384;
        int row = (rr == 0) ? 0 : (512 + rr);
        ws[OFF_G + v * GSTRIDE + row * 384 + col] = 0.f;
    } else if (i >= 3584 && i < 9728) {    // S1: 96 waves, shuffle-reduce
        int j = i - 3584;
        int w = j >> 6, lane = j & 63;
        int v = w >> 5, n = w & 31;
        const float* w1p = (v == 0) ? qw1 : ((v == 1) ? kw1 : vw1);
        float s = 0.f;
#pragma unroll
        for (int k = 0; k < 8; k++) s += w1p[(lane + 64 * k) * 32 + n];
#pragma unroll
        for (int off = 32; off > 0; off >>= 1) s += __shfl_xor(s, off);
        if (lane == 0) ws[OFF_S1 + w] = s;
    }
}

// ---------------------------------------------------------------------------
// k_corr: G[v][h+1][ci][n][dx] = sum_u x[ci][h][u] * w1v[u+1-dx][n]
// grid (64 hblk, 3 ci, 3 v), block 256 = 8 rows x 32 n. float4 G stores.
// ---------------------------------------------------------------------------
__global__ __launch_bounds__(256) void k_corr(const float* __restrict__ x,
                                              const float* __restrict__ qw1,
                                              const float* __restrict__ kw1,
                                              const float* __restrict__ vw1,
                                              float* __restrict__ ws) {
    const int h0 = blockIdx.x * 8, ci = blockIdx.y, v = blockIdx.z;
    const int tid = threadIdx.x;
    __shared__ __align__(16) float ws1t[32 * 516];

    const float* w1f = (v == 0) ? qw1 : ((v == 1) ? kw1 : vw1);
    for (int i = tid; i < 4096; i += 256) {       // transpose-stage w1
        int n_ = i & 31, u = (i >> 5) * 4;
        float a = w1f[(u + 0) * 32 + n_];
        float b = w1f[(u + 1) * 32 + n_];
        float c = w1f[(u + 2) * 32 + n_];
        float d = w1f[(u + 3) * 32 + n_];
        *(float4*)&ws1t[n_ * 516 + u] = make_float4(a, b, c, d);
    }
    if (tid < 32) *(float4*)&ws1t[tid * 516 + 512] = make_float4(0.f, 0.f, 0.f, 0.f);
    __syncthreads();

    const int hp = tid >> 5, n = tid & 31;
    const float* xrow = x + ci * 262144 + (h0 + hp) * 512;
    float a0 = 0.f, a1 = 0.f, a2 = 0.f, pq = 0.f;
    float4 cq = *(float4*)&ws1t[n * 516];
#pragma unroll 4
    for (int k = 0; k < 128; k++) {
        float4 nq = *(float4*)&ws1t[n * 516 + 4 * k + 4];
        float4 x4 = *(const float4*)&xrow[4 * k];
        a1 = fmaf(x4.x, cq.x, a1); a1 = fmaf(x4.y, cq.y, a1);
        a1 = fmaf(x4.z, cq.z, a1); a1 = fmaf(x4.w, cq.w, a1);
        a0 = fmaf(x4.x, cq.y, a0); a0 = fmaf(x4.y, cq.z, a0);
        a0 = fmaf(x4.z, cq.w, a0); a0 = fmaf(x4.w, nq.x, a0);
        a2 = fmaf(x4.x, pq,   a2); a2 = fmaf(x4.y, cq.x, a2);
        a2 = fmaf(x4.z, cq.y, a2); a2 = fmaf(x4.w, cq.z, a2);
        pq = cq.w; cq = nq;
    }
    float* g = ws + OFF_G + v * GSTRIDE + (h0 + hp + 1) * 384 + ci * 128 + n * 4;
    *(float4*)g = make_float4(a0, a1, a2, 0.f);
}

// ---------------------------------------------------------------------------
// k_mlp: one wave per (v,c). Per 16-h chunk: lane computes 8 y1 values
// (n = lane&31, h = H + j with H = hc*16 + 8*(lane>>5)) via 27-tap FMA +
// sigmoid from a rolling 4-slot register row file (3 float4 loads per row),
// packs them as the bf16 A-fragment; B-fragment = w2[h][o=lane&31]; one
// v_mfma_f32_32x32x16_bf16 accumulates the 32n x 32o tile. Epilogue: +b2,
// sigmoid, split-heads scatter straight into QKV (C/D layout: col=lane&31=o,
// row=(reg&3)+8*(reg>>2)+4*(lane>>5)=n).
// grid (256 cblk, 3 v) x 192 thr (3 waves = 3 c) -> exactly 3 blocks/CU.
// ---------------------------------------------------------------------------
struct MlpPtrs {
    const float* b1[3];
    const float* w2[3];
    const float* b2[3];
};

__global__ __launch_bounds__(192) void k_mlp(const float* __restrict__ cwp,
                                             const float* __restrict__ cbp,
                                             MlpPtrs mp, float* __restrict__ ws) {
    const int v = blockIdx.y;
    const int wv = threadIdx.x >> 6;
    const int lane = threadIdx.x & 63;
    const int c = blockIdx.x * 3 + wv;
    const int n = lane & 31;               // A-row (m) AND B-col (o)
    const int half = lane >> 5;

    const float* gv  = ws + OFF_G + v * GSTRIDE;
    const float* w2p = mp.w2[v];

    float cwr[3][9];                       // [dy][ci*3+dx]
#pragma unroll
    for (int dy = 0; dy < 3; dy++)
#pragma unroll
        for (int q = 0; q < 9; q++)
            cwr[dy][q] = cwp[c * 27 + (q / 3) * 9 + dy * 3 + (q % 3)];
    const float base = mp.b1[v][n] + cbp[c] * ws[OFF_S1 + v * 32 + n];

    f32x16 acc;
#pragma unroll
    for (int r = 0; r < 16; r++) acc[r] = 0.f;

    for (int hc = 0; hc < 32; hc++) {
        const int H = hc * 16 + half * 8;          // this lane's first h
        const float* rp = gv + H * 384 + n * 4;

        // B fragment: w2[H+b][o]
        bf16x8 bf;
#pragma unroll
        for (int b = 0; b < 8; b++) bf[b] = f2bf(w2p[(H + b) * 32 + n]);

        // preload rows H..H+3 into slots 0..3 (rows <= 513: in-bounds)
        float R[4][9];
#pragma unroll
        for (int s = 0; s < 4; s++) {
            float4 t0 = *(const float4*)(rp + s * 384);
            float4 t1 = *(const float4*)(rp + s * 384 + 128);
            float4 t2 = *(const float4*)(rp + s * 384 + 256);
            R[s][0] = t0.x; R[s][1] = t0.y; R[s][2] = t0.z;
            R[s][3] = t1.x; R[s][4] = t1.y; R[s][5] = t1.z;
            R[s][6] = t2.x; R[s][7] = t2.y; R[s][8] = t2.z;
        }

        bf16x8 af;
#pragma unroll
        for (int j = 0; j < 8; j++) {
            float s0 = base, s1 = 0.f, s2 = 0.f;
#pragma unroll
            for (int q = 0; q < 9; q++) {
                s0 = fmaf(cwr[0][q], R[(j + 0) & 3][q], s0);
                s1 = fmaf(cwr[1][q], R[(j + 1) & 3][q], s1);
                s2 = fmaf(cwr[2][q], R[(j + 2) & 3][q], s2);
            }
            if (j < 6) {                   // refill slot j&3 with row H+j+4 (<=513)
                const float* q4 = rp + (j + 4) * 384;
                float4 t0 = *(const float4*)(q4);
                float4 t1 = *(const float4*)(q4 + 128);
                float4 t2 = *(const float4*)(q4 + 256);
                R[j & 3][0] = t0.x; R[j & 3][1] = t0.y; R[j & 3][2] = t0.z;
                R[j & 3][3] = t1.x; R[j & 3][4] = t1.y; R[j & 3][5] = t1.z;
                R[j & 3][6] = t2.x; R[j & 3][7] = t2.y; R[j & 3][8] = t2.z;
            }
            af[j] = f2bf(sigm((s0 + s1) + s2));
        }
        acc = __builtin_amdgcn_mfma_f32_32x32x16_bf16(af, bf, acc, 0, 0, 0);
    }

    // epilogue: +b2, sigmoid, split-heads scatter into QKV
    const float b2v = mp.b2[v][n];                 // o == n
    float* qout = ws + OFF_QKV + v * 786432;
#pragma unroll
    for (int r = 0; r < 16; r++) {
        int nn = (r & 3) + 8 * (r >> 2) + 4 * half;
        float m = sigm(acc[r] + b2v);
        int head = ((n & 1) << 1) | (nn & 1);      // (head1,head2)
        int sidx = ((n >> 1) << 4) | (nn >> 1);    // hidx*16+widx
        qout[head * 196608 + c * 256 + sidx] = m;
    }
}

// ---------------------------------------------------------------------------
// k_qk: scores[head] = temp[head] * Q @ K^T   (768x768, K=256)
// 64x64 tiles, 4x4 micro-tile, LDS [k][row] layout, conflict-free staging.
// ---------------------------------------------------------------------------
__global__ __launch_bounds__(256) void k_qk(const float* __restrict__ tempr,
                                            float* __restrict__ ws) {
    const int i0 = blockIdx.x * 64, j0 = blockIdx.y * 64, head = blockIdx.z;
    const float* Q = ws + OFF_QKV + head * 196608;             // v=0
    const float* K = ws + OFF_QKV + 786432 + head * 196608;    // v=1
    float* S = ws + OFF_SC + head * 589824;
    const float temp = tempr[head];
    __shared__ __align__(16) float Qs[64][68];
    __shared__ __align__(16) float Ks[64][68];
    const int tid = threadIdx.x, ty = tid >> 4, tx = tid & 15;
    const int sr = tid & 15, sk4 = (tid >> 4) * 4;   // staging map
    float acc[4][4] = {};

    for (int kc = 0; kc < 256; kc += 64) {
        __syncthreads();
#pragma unroll
        for (int it = 0; it < 4; it++) {
            int r = sr + 16 * it;
            float4 q = *(const float4*)&Q[(i0 + r) * 256 + kc + sk4];
            Qs[sk4 + 0][r] = q.x; Qs[sk4 + 1][r] = q.y;
            Qs[sk4 + 2][r] = q.z; Qs[sk4 + 3][r] = q.w;
            float4 k = *(const float4*)&K[(j0 + r) * 256 + kc + sk4];
            Ks[sk4 + 0][r] = k.x; Ks[sk4 + 1][r] = k.y;
            Ks[sk4 + 2][r] = k.z; Ks[sk4 + 3][r] = k.w;
        }
        __syncthreads();
#pragma unroll
        for (int k = 0; k < 64; k++) {
            float4 a = *(float4*)&Qs[k][ty * 4];
            float4 b = *(float4*)&Ks[k][tx * 4];
            float av[4] = {a.x, a.y, a.z, a.w}, bv[4] = {b.x, b.y, b.z, b.w};
#pragma unroll
            for (int e = 0; e < 4; e++)
#pragma unroll
                for (int f = 0; f < 4; f++) acc[e][f] = fmaf(av[e], bv[f], acc[e][f]);
        }
    }
#pragma unroll
    for (int e = 0; e < 4; e++) {
        float4 r = make_float4(acc[e][0] * temp, acc[e][1] * temp,
                               acc[e][2] * temp, acc[e][3] * temp);
        *(float4*)&S[(i0 + ty * 4 + e) * 768 + j0 + tx * 4] = r;
    }
}

// ---------------------------------------------------------------------------
// k_soft: row softmax over 768. 256-thr blocks, 4 rows/block (one per wave).
// ---------------------------------------------------------------------------
__global__ __launch_bounds__(256) void k_soft(float* __restrict__ ws) {
    float* row = ws + OFF_SC + ((size_t)blockIdx.x * 4 + (threadIdx.x >> 6)) * 768;
    const int t = threadIdx.x & 63;
    float4 v0 = *(float4*)&row[t * 12];
    float4 v1 = *(float4*)&row[t * 12 + 4];
    float4 v2 = *(float4*)&row[t * 12 + 8];
    float m0 = fmaxf(fmaxf(v0.x, v0.y), fmaxf(v0.z, v0.w));
    float m1 = fmaxf(fmaxf(v1.x, v1.y), fmaxf(v1.z, v1.w));
    float m2 = fmaxf(fmaxf(v2.x, v2.y), fmaxf(v2.z, v2.w));
    float m = fmaxf(fmaxf(m0, m1), m2);
#pragma unroll
    for (int off = 32; off > 0; off >>= 1) m = fmaxf(m, __shfl_xor(m, off));
    v0.x = __expf(v0.x - m); v0.y = __expf(v0.y - m); v0.z = __expf(v0.z - m); v0.w = __expf(v0.w - m);
    v1.x = __expf(v1.x - m); v1.y = __expf(v1.y - m); v1.z = __expf(v1.z - m); v1.w = __expf(v1.w - m);
    v2.x = __expf(v2.x - m); v2.y = __expf(v2.y - m); v2.z = __expf(v2.z - m); v2.w = __expf(v2.w - m);
    float s = v0.x + v0.y + v0.z + v0.w + v1.x + v1.y + v1.z + v1.w + v2.x + v2.y + v2.z + v2.w;
#pragma unroll
    for (int off = 32; off > 0; off >>= 1) s += __shfl_xor(s, off);
    float inv = __builtin_amdgcn_rcpf(s);
    v0.x *= inv; v0.y *= inv; v0.z *= inv; v0.w *= inv;
    v1.x *= inv; v1.y *= inv; v1.z *= inv; v1.w *= inv;
    v2.x *= inv; v2.y *= inv; v2.z *= inv; v2.w *= inv;
    *(float4*)&row[t * 12]     = v0;
    *(float4*)&row[t * 12 + 4] = v1;
    *(float4*)&row[t * 12 + 8] = v2;
}

// ---------------------------------------------------------------------------
// k_av: ATT[head] = attn @ V  (768x256, K=768). 32x64 tiles (384 blocks),
// 2x4 micro-tile, conflict-free staging.
// ---------------------------------------------------------------------------
__global__ __launch_bounds__(256) void k_av(float* __restrict__ ws) {
    const int i0 = blockIdx.x * 32, s0 = blockIdx.y * 64, head = blockIdx.z;
    const float* A = ws + OFF_SC + head * 589824;
    const float* V = ws + OFF_QKV + 2 * 786432 + head * 196608;
    float* O = ws + OFF_ATT + head * 196608;
    __shared__ __align__(16) float As[64][34];
    __shared__ __align__(16) float Bs[64][68];
    const int tid = threadIdx.x, ty = tid >> 4, tx = tid & 15;
    const int sr = tid & 31, sq = tid >> 5;          // staging map
    float acc[2][4] = {};

    for (int dc = 0; dc < 768; dc += 64) {
        __syncthreads();
#pragma unroll
        for (int it = 0; it < 2; it++) {
            int k4 = sq * 4 + 32 * it;
            float4 a = *(const float4*)&A[(i0 + sr) * 768 + dc + k4];
            As[k4 + 0][sr] = a.x; As[k4 + 1][sr] = a.y;
            As[k4 + 2][sr] = a.z; As[k4 + 3][sr] = a.w;
        }
        for (int idx = tid; idx < 1024; idx += 256) {
            int r = idx >> 4, k4 = (idx & 15) * 4;
            *(float4*)&Bs[r][k4] = *(const float4*)&V[(dc + r) * 256 + s0 + k4];
        }
        __syncthreads();
#pragma unroll
        for (int k = 0; k < 64; k++) {
            float a0 = As[k][ty * 2], a1 = As[k][ty * 2 + 1];
            float4 b = *(float4*)&Bs[k][tx * 4];
            acc[0][0] = fmaf(a0, b.x, acc[0][0]); acc[0][1] = fmaf(a0, b.y, acc[0][1]);
            acc[0][2] = fmaf(a0, b.z, acc[0][2]); acc[0][3] = fmaf(a0, b.w, acc[0][3]);
            acc[1][0] = fmaf(a1, b.x, acc[1][0]); acc[1][1] = fmaf(a1, b.y, acc[1][1]);
            acc[1][2] = fmaf(a1, b.z, acc[1][2]); acc[1][3] = fmaf(a1, b.w, acc[1][3]);
        }
    }
#pragma unroll
    for (int e = 0; e < 2; e++) {
        float4 r = make_float4(acc[e][0], acc[e][1], acc[e][2], acc[e][3]);
        *(float4*)&O[(i0 + ty * 2 + e) * 256 + s0 + tx * 4] = r;
    }
}

// ---------------------------------------------------------------------------
// k_ffn: fused pointwise(3->12) + dwconv3x3 + gelu-gate + pointwise(6->3)
// + residual, f32 store. 32x16 pixel tiles (512 blocks), 34x18 halo in LDS.
// ---------------------------------------------------------------------------
struct FfnPtrs { const float* p[6]; };  // pi_w, pi_b, dw_w, dw_b, po_w, po_b

__global__ __launch_bounds__(256) void k_ffn(const float* __restrict__ ws,
                                             const float* __restrict__ x,
                                             FfnPtrs fp,
                                             float* __restrict__ out) {
    const int x0 = blockIdx.x * 32, y0 = blockIdx.y * 16;
    __shared__ float wsm[192];
    __shared__ float p[12][612];
    const int tid = threadIdx.x;
    if (tid < 36)       wsm[tid] = fp.p[0][tid];          // pi_w (12,3)
    else if (tid < 48)  wsm[tid] = fp.p[1][tid - 36];     // pi_b (12)
    else if (tid < 156) wsm[tid] = fp.p[2][tid - 48];     // dw_w (12,9)
    else if (tid < 168) wsm[tid] = fp.p[3][tid - 156];    // dw_b (12)
    else if (tid < 186) wsm[tid] = fp.p[4][tid - 168];    // po_w (3,6)
    else if (tid < 189) wsm[tid] = fp.p[5][tid - 186];    // po_b (3)
    __syncthreads();

    const float* A = ws + OFF_ATT;
    for (int i = tid; i < 612; i += 256) {
        int py = i / 34, px = i % 34;
        int gy = y0 + py - 1, gx = x0 + px - 1;
        bool in = ((unsigned)gy < 512u) && ((unsigned)gx < 512u);
        float a0 = 0.f, a1 = 0.f, a2 = 0.f;
        if (in) {
            int b = gy * 512 + gx;
            a0 = A[b]; a1 = A[262144 + b]; a2 = A[524288 + b];
        }
#pragma unroll
        for (int j = 0; j < 12; j++) {
            float t = in ? (wsm[36 + j] + wsm[j * 3] * a0 + wsm[j * 3 + 1] * a1
                            + wsm[j * 3 + 2] * a2)
                         : 0.f;
            p[j][i] = t;
        }
    }
    __syncthreads();

#pragma unroll
    for (int it = 0; it < 2; it++) {
        int pl = tid + it * 256;
        int ly = pl >> 5, lx = pl & 31;
        float z[12];
#pragma unroll
        for (int j = 0; j < 12; j++) {
            const float* dw = &wsm[48 + j * 9];
            const float* pr = &p[j][ly * 34 + lx];
            z[j] = wsm[156 + j]
                 + dw[0] * pr[0]  + dw[1] * pr[1]  + dw[2] * pr[2]
                 + dw[3] * pr[34] + dw[4] * pr[35] + dw[5] * pr[36]
                 + dw[6] * pr[68] + dw[7] * pr[69] + dw[8] * pr[70];
        }
        float g[6];
#pragma unroll
        for (int j = 0; j < 6; j++) {
            float xx = z[j];
            g[j] = 0.5f * xx * (1.f + erff(xx * 0.70710678118f)) * z[6 + j];
        }
        int b = (y0 + ly) * 512 + (x0 + lx);
#pragma unroll
        for (int co = 0; co < 3; co++) {
            float r = wsm[186 + co];
#pragma unroll
            for (int j = 0; j < 6; j++) r = fmaf(wsm[168 + co * 6 + j], g[j], r);
            r += x[co * 262144 + b];             // residual
            out[co * 262144 + b] = r;
        }
    }
}

// ---------------------------------------------------------------------------
extern "C" void kernel_launch(void* const* d_in, const int* in_sizes, int n_in,
                              void* d_out, int out_size, void* d_ws, size_t ws_size,
                              hipStream_t stream) {
    float* ws = (float*)d_ws;
    float* out = (float*)d_out;
    const float* x   = (const float*)d_in[0];
    const float* cw  = (const float*)d_in[1];
    const float* cb  = (const float*)d_in[2];
    const float* qw1 = (const float*)d_in[3];
    const float* kw1 = (const float*)d_in[7];
    const float* vw1 = (const float*)d_in[11];
    const float* temp= (const float*)d_in[15];

    MlpPtrs mp;
    mp.b1[0] = (const float*)d_in[4];  mp.w2[0] = (const float*)d_in[5];  mp.b2[0] = (const float*)d_in[6];
    mp.b1[1] = (const float*)d_in[8];  mp.w2[1] = (const float*)d_in[9];  mp.b2[1] = (const float*)d_in[10];
    mp.b1[2] = (const float*)d_in[12]; mp.w2[2] = (const float*)d_in[13]; mp.b2[2] = (const float*)d_in[14];

    FfnPtrs fp;
    for (int i = 0; i < 6; i++) fp.p[i] = (const float*)d_in[16 + i];

    k_prep<<<38, 256, 0, stream>>>(qw1, kw1, vw1, ws);
    k_corr<<<dim3(64, 3, 3), 256, 0, stream>>>(x, qw1, kw1, vw1, ws);
    k_mlp <<<dim3(256, 3), 192, 0, stream>>>(cw, cb, mp, ws);
    k_qk  <<<dim3(12, 12, 4), 256, 0, stream>>>(temp, ws);
    k_soft<<<768, 256, 0, stream>>>(ws);
    k_av  <<<dim3(24, 4, 4), 256, 0, stream>>>(ws);
    k_ffn <<<dim3(16, 32), 256, 0, stream>>>(ws, x, fp, out);
}

// Round 10
// 295.482 us; speedup vs baseline: 1.1988x; 1.0109x over previous
//
#include <hip/hip_runtime.h>
#include <math.h>

// ---------------------------------------------------------------------------
// Restormer block, B=1 DIM=3 NC=512 HEADS=2 -> CT=768, NT=32, HID=6. f32 I/O.
//
// conv3x3 (+) MLP-stage1 collapsed through G = row-correlations of x with w1
// columns. R9 moved MLP stage-2 to MFMA (one wave per (v,c), 32x32x16 bf16).
// R10: k_mlp 2-way K-split (4 waves/block = 2c x 2ksplit, LDS-reduced) for
// 2x wave parallelism, and w2 pre-packed to bf16 B-fragments in k_prep
// (stored in the then-idle scores region; one dwordx4 per hc instead of
// 8 loads + 8 cvts).
// ---------------------------------------------------------------------------

__device__ __forceinline__ float sigm(float s) {
    return __builtin_amdgcn_rcpf(1.f + __expf(-s));
}

using bf16x8 = __attribute__((ext_vector_type(8))) short;   // 8 bf16 (4 VGPRs)
using f32x16 = __attribute__((ext_vector_type(16))) float;

__device__ __forceinline__ short f2bf(float f) {
    union { __bf16 h; short s; } u;
    u.h = (__bf16)f;                    // HW cvt, RNE
    return u.s;
}

// ---- f32 workspace layout (element offsets) -------------------------------
static constexpr int OFF_G   = 0;         // [3v][515 rows][3ci][32n][4]; rows 0,513,514 zero pad
static constexpr int GSTRIDE = 197760;    // 515*384
static constexpr int OFF_S1  = 593280;    // [3v][32] column sums of w1
static constexpr int OFF_QKV = 593408;    // [3v][4head][768c][256s]
static constexpr int OFF_SC  = 2952704;   // [4head][768][768] scores; ALSO (before k_qk)
                                          //   w2 bf16 B-fragment pack [3v][32hc][64lane][uint4]
static constexpr int OFF_ATT = 5312000;   // [4head][768][256] == (3,512,512) flat
// total 6098432 floats = 24.4 MB

struct MlpPtrs {
    const float* b1[3];
    const float* w2[3];
    const float* b2[3];
};

// ---------------------------------------------------------------------------
// k_prep: zero G pad rows; S1[v][n] = sum_u w1v[u][n]; pack w2 into bf16
// B-fragments at OFF_SC (region is free until k_qk).
// segments: [0,3456) pads | [3584,9728) S1 | [9728,15872) w2 pack
// ---------------------------------------------------------------------------
__global__ __launch_bounds__(256) void k_prep(const float* __restrict__ qw1,
                                              const float* __restrict__ kw1,
                                              const float* __restrict__ vw1,
                                              MlpPtrs mp,
                                              float* __restrict__ ws) {
    int i = blockIdx.x * 256 + threadIdx.x;
    if (i < 3456) {                        // zero G pad rows 0,513,514 per v
        int v = i / 1152, rr = (i % 1152) / 384, col = i % 384;
        int row = (rr == 0) ? 0 : (512 + rr);
        ws[OFF_G + v * GSTRIDE + row * 384 + col] = 0.f;
    } else if (i >= 3584 && i < 9728) {    // S1: 96 waves, shuffle-reduce
        int j = i - 3584;
        int w = j >> 6, lane = j & 63;
        int v = w >> 5, n = w & 31;
        const float* w1p = (v == 0) ? qw1 : ((v == 1) ? kw1 : vw1);
        float s = 0.f;
#pragma unroll
        for (int k = 0; k < 8; k++) s += w1p[(lane + 64 * k) * 32 + n];
#pragma unroll
        for (int off = 32; off > 0; off >>= 1) s += __shfl_xor(s, off);
        if (lane == 0) ws[OFF_S1 + w] = s;
    } else if (i >= 9728 && i < 9728 + 6144) {   // w2 -> bf16 B-fragments
        int j = i - 9728;                  // j = v*2048 + hc*64 + lane
        int v = j >> 11, r = j & 2047;
        int hc = r >> 6, lane = r & 63;
        int o = lane & 31, half = lane >> 5;
        int H = hc * 16 + half * 8;
        const float* w2p = mp.w2[v];
        unsigned int d[4];
#pragma unroll
        for (int t = 0; t < 4; t++) {
            unsigned short lo = (unsigned short)f2bf(w2p[(H + 2 * t) * 32 + o]);
            unsigned short hi = (unsigned short)f2bf(w2p[(H + 2 * t + 1) * 32 + o]);
            d[t] = ((unsigned int)hi << 16) | lo;
        }
        uint4* dst = (uint4*)(ws + OFF_SC);
        dst[j] = make_uint4(d[0], d[1], d[2], d[3]);
    }
}

// ---------------------------------------------------------------------------
// k_corr: G[v][h+1][ci][n][dx] = sum_u x[ci][h][u] * w1v[u+1-dx][n]
// grid (64 hblk, 3 ci, 3 v), block 256 = 8 rows x 32 n. float4 G stores.
// ---------------------------------------------------------------------------
__global__ __launch_bounds__(256) void k_corr(const float* __restrict__ x,
                                              const float* __restrict__ qw1,
                                              const float* __restrict__ kw1,
                                              const float* __restrict__ vw1,
                                              float* __restrict__ ws) {
    const int h0 = blockIdx.x * 8, ci = blockIdx.y, v = blockIdx.z;
    const int tid = threadIdx.x;
    __shared__ __align__(16) float ws1t[32 * 516];

    const float* w1f = (v == 0) ? qw1 : ((v == 1) ? kw1 : vw1);
    for (int i = tid; i < 4096; i += 256) {       // transpose-stage w1
        int n_ = i & 31, u = (i >> 5) * 4;
        float a = w1f[(u + 0) * 32 + n_];
        float b = w1f[(u + 1) * 32 + n_];
        float c = w1f[(u + 2) * 32 + n_];
        float d = w1f[(u + 3) * 32 + n_];
        *(float4*)&ws1t[n_ * 516 + u] = make_float4(a, b, c, d);
    }
    if (tid < 32) *(float4*)&ws1t[tid * 516 + 512] = make_float4(0.f, 0.f, 0.f, 0.f);
    __syncthreads();

    const int hp = tid >> 5, n = tid & 31;
    const float* xrow = x + ci * 262144 + (h0 + hp) * 512;
    float a0 = 0.f, a1 = 0.f, a2 = 0.f, pq = 0.f;
    float4 cq = *(float4*)&ws1t[n * 516];
#pragma unroll 4
    for (int k = 0; k < 128; k++) {
        float4 nq = *(float4*)&ws1t[n * 516 + 4 * k + 4];
        float4 x4 = *(const float4*)&xrow[4 * k];
        a1 = fmaf(x4.x, cq.x, a1); a1 = fmaf(x4.y, cq.y, a1);
        a1 = fmaf(x4.z, cq.z, a1); a1 = fmaf(x4.w, cq.w, a1);
        a0 = fmaf(x4.x, cq.y, a0); a0 = fmaf(x4.y, cq.z, a0);
        a0 = fmaf(x4.z, cq.w, a0); a0 = fmaf(x4.w, nq.x, a0);
        a2 = fmaf(x4.x, pq,   a2); a2 = fmaf(x4.y, cq.x, a2);
        a2 = fmaf(x4.z, cq.y, a2); a2 = fmaf(x4.w, cq.z, a2);
        pq = cq.w; cq = nq;
    }
    float* g = ws + OFF_G + v * GSTRIDE + (h0 + hp + 1) * 384 + ci * 128 + n * 4;
    *(float4*)g = make_float4(a0, a1, a2, 0.f);
}

// ---------------------------------------------------------------------------
// k_mlp: 2 waves per (v,c), each owns half the K=512 (16 of 32 hc chunks).
// Per 16-h chunk a lane computes 8 y1 values (27-tap FMA + sigmoid, rolling
// 4-slot register rows), packs bf16 A-fragment; B-fragment = one dwordx4
// from the w2 pre-pack; one v_mfma_f32_32x32x16_bf16. ks=1 waves dump their
// acc to LDS; ks=0 waves add and run the epilogue (+b2, sigmoid, split-heads
// scatter into QKV). Block 256 = 2c x 2ks; grid (384, 3) = 1152 blocks.
// ---------------------------------------------------------------------------
__global__ __launch_bounds__(256) void k_mlp(const float* __restrict__ cwp,
                                             const float* __restrict__ cbp,
                                             MlpPtrs mp, float* __restrict__ ws) {
    const int v = blockIdx.y;
    const int wv = threadIdx.x >> 6;
    const int lane = threadIdx.x & 63;
    const int cl = wv >> 1, ks = wv & 1;
    const int c = blockIdx.x * 2 + cl;
    const int n = lane & 31;               // A-row (m) AND B-col (o)
    const int half = lane >> 5;
    __shared__ float red[2][16][64];       // 8 KB reduction buffer

    const float* gv = ws + OFF_G + v * GSTRIDE;
    const uint4* w2pk = (const uint4*)(ws + OFF_SC) + (size_t)v * 2048 + lane;

    float cwr[3][9];                       // [dy][ci*3+dx]
#pragma unroll
    for (int dy = 0; dy < 3; dy++)
#pragma unroll
        for (int q = 0; q < 9; q++)
            cwr[dy][q] = cwp[c * 27 + (q / 3) * 9 + dy * 3 + (q % 3)];
    const float base = mp.b1[v][n] + cbp[c] * ws[OFF_S1 + v * 32 + n];

    f32x16 acc;
#pragma unroll
    for (int r = 0; r < 16; r++) acc[r] = 0.f;

    for (int hcl = 0; hcl < 16; hcl++) {
        const int hc = ks * 16 + hcl;
        const int H = hc * 16 + half * 8;          // this lane's first h
        const float* rp = gv + H * 384 + n * 4;

        // B fragment: one dwordx4 from the pre-pack
        union { uint4 u; bf16x8 b; } bw;
        bw.u = w2pk[hc * 64];

        // preload rows H..H+3 into slots 0..3 (rows <= 513: in-bounds)
        float R[4][9];
#pragma unroll
        for (int s = 0; s < 4; s++) {
            float4 t0 = *(const float4*)(rp + s * 384);
            float4 t1 = *(const float4*)(rp + s * 384 + 128);
            float4 t2 = *(const float4*)(rp + s * 384 + 256);
            R[s][0] = t0.x; R[s][1] = t0.y; R[s][2] = t0.z;
            R[s][3] = t1.x; R[s][4] = t1.y; R[s][5] = t1.z;
            R[s][6] = t2.x; R[s][7] = t2.y; R[s][8] = t2.z;
        }

        bf16x8 af;
#pragma unroll
        for (int j = 0; j < 8; j++) {
            float s0 = base, s1 = 0.f, s2 = 0.f;
#pragma unroll
            for (int q = 0; q < 9; q++) {
                s0 = fmaf(cwr[0][q], R[(j + 0) & 3][q], s0);
                s1 = fmaf(cwr[1][q], R[(j + 1) & 3][q], s1);
                s2 = fmaf(cwr[2][q], R[(j + 2) & 3][q], s2);
            }
            if (j < 6) {                   // refill slot j&3 with row H+j+4 (<=513)
                const float* q4 = rp + (j + 4) * 384;
                float4 t0 = *(const float4*)(q4);
                float4 t1 = *(const float4*)(q4 + 128);
                float4 t2 = *(const float4*)(q4 + 256);
                R[j & 3][0] = t0.x; R[j & 3][1] = t0.y; R[j & 3][2] = t0.z;
                R[j & 3][3] = t1.x; R[j & 3][4] = t1.y; R[j & 3][5] = t1.z;
                R[j & 3][6] = t2.x; R[j & 3][7] = t2.y; R[j & 3][8] = t2.z;
            }
            af[j] = f2bf(sigm((s0 + s1) + s2));
        }
        acc = __builtin_amdgcn_mfma_f32_32x32x16_bf16(af, bw.b, acc, 0, 0, 0);
    }

    if (ks == 1) {
#pragma unroll
        for (int r = 0; r < 16; r++) red[cl][r][lane] = acc[r];
    }
    __syncthreads();
    if (ks == 0) {
        const float b2v = mp.b2[v][n];             // o == n
        float* qout = ws + OFF_QKV + v * 786432;
#pragma unroll
        for (int r = 0; r < 16; r++) {
            float a = acc[r] + red[cl][r][lane];
            int nn = (r & 3) + 8 * (r >> 2) + 4 * half;
            float m = sigm(a + b2v);
            int head = ((n & 1) << 1) | (nn & 1);  // (head1,head2)
            int sidx = ((n >> 1) << 4) | (nn >> 1);
            qout[head * 196608 + c * 256 + sidx] = m;
        }
    }
}

// ---------------------------------------------------------------------------
// k_qk: scores[head] = temp[head] * Q @ K^T   (768x768, K=256)
// 64x64 tiles, 4x4 micro-tile, LDS [k][row] layout, conflict-free staging.
// ---------------------------------------------------------------------------
__global__ __launch_bounds__(256) void k_qk(const float* __restrict__ tempr,
                                            float* __restrict__ ws) {
    const int i0 = blockIdx.x * 64, j0 = blockIdx.y * 64, head = blockIdx.z;
    const float* Q = ws + OFF_QKV + head * 196608;             // v=0
    const float* K = ws + OFF_QKV + 786432 + head * 196608;    // v=1
    float* S = ws + OFF_SC + head * 589824;
    const float temp = tempr[head];
    __shared__ __align__(16) float Qs[64][68];
    __shared__ __align__(16) float Ks[64][68];
    const int tid = threadIdx.x, ty = tid >> 4, tx = tid & 15;
    const int sr = tid & 15, sk4 = (tid >> 4) * 4;   // staging map
    float acc[4][4] = {};

    for (int kc = 0; kc < 256; kc += 64) {
        __syncthreads();
#pragma unroll
        for (int it = 0; it < 4; it++) {
            int r = sr + 16 * it;
            float4 q = *(const float4*)&Q[(i0 + r) * 256 + kc + sk4];
            Qs[sk4 + 0][r] = q.x; Qs[sk4 + 1][r] = q.y;
            Qs[sk4 + 2][r] = q.z; Qs[sk4 + 3][r] = q.w;
            float4 k = *(const float4*)&K[(j0 + r) * 256 + kc + sk4];
            Ks[sk4 + 0][r] = k.x; Ks[sk4 + 1][r] = k.y;
            Ks[sk4 + 2][r] = k.z; Ks[sk4 + 3][r] = k.w;
        }
        __syncthreads();
#pragma unroll
        for (int k = 0; k < 64; k++) {
            float4 a = *(float4*)&Qs[k][ty * 4];
            float4 b = *(float4*)&Ks[k][tx * 4];
            float av[4] = {a.x, a.y, a.z, a.w}, bv[4] = {b.x, b.y, b.z, b.w};
#pragma unroll
            for (int e = 0; e < 4; e++)
#pragma unroll
                for (int f = 0; f < 4; f++) acc[e][f] = fmaf(av[e], bv[f], acc[e][f]);
        }
    }
#pragma unroll
    for (int e = 0; e < 4; e++) {
        float4 r = make_float4(acc[e][0] * temp, acc[e][1] * temp,
                               acc[e][2] * temp, acc[e][3] * temp);
        *(float4*)&S[(i0 + ty * 4 + e) * 768 + j0 + tx * 4] = r;
    }
}

// ---------------------------------------------------------------------------
// k_soft: row softmax over 768. 256-thr blocks, 4 rows/block (one per wave).
// ---------------------------------------------------------------------------
__global__ __launch_bounds__(256) void k_soft(float* __restrict__ ws) {
    float* row = ws + OFF_SC + ((size_t)blockIdx.x * 4 + (threadIdx.x >> 6)) * 768;
    const int t = threadIdx.x & 63;
    float4 v0 = *(float4*)&row[t * 12];
    float4 v1 = *(float4*)&row[t * 12 + 4];
    float4 v2 = *(float4*)&row[t * 12 + 8];
    float m0 = fmaxf(fmaxf(v0.x, v0.y), fmaxf(v0.z, v0.w));
    float m1 = fmaxf(fmaxf(v1.x, v1.y), fmaxf(v1.z, v1.w));
    float m2 = fmaxf(fmaxf(v2.x, v2.y), fmaxf(v2.z, v2.w));
    float m = fmaxf(fmaxf(m0, m1), m2);
#pragma unroll
    for (int off = 32; off > 0; off >>= 1) m = fmaxf(m, __shfl_xor(m, off));
    v0.x = __expf(v0.x - m); v0.y = __expf(v0.y - m); v0.z = __expf(v0.z - m); v0.w = __expf(v0.w - m);
    v1.x = __expf(v1.x - m); v1.y = __expf(v1.y - m); v1.z = __expf(v1.z - m); v1.w = __expf(v1.w - m);
    v2.x = __expf(v2.x - m); v2.y = __expf(v2.y - m); v2.z = __expf(v2.z - m); v2.w = __expf(v2.w - m);
    float s = v0.x + v0.y + v0.z + v0.w + v1.x + v1.y + v1.z + v1.w + v2.x + v2.y + v2.z + v2.w;
#pragma unroll
    for (int off = 32; off > 0; off >>= 1) s += __shfl_xor(s, off);
    float inv = __builtin_amdgcn_rcpf(s);
    v0.x *= inv; v0.y *= inv; v0.z *= inv; v0.w *= inv;
    v1.x *= inv; v1.y *= inv; v1.z *= inv; v1.w *= inv;
    v2.x *= inv; v2.y *= inv; v2.z *= inv; v2.w *= inv;
    *(float4*)&row[t * 12]     = v0;
    *(float4*)&row[t * 12 + 4] = v1;
    *(float4*)&row[t * 12 + 8] = v2;
}

// ---------------------------------------------------------------------------
// k_av: ATT[head] = attn @ V  (768x256, K=768). 32x64 tiles (384 blocks),
// 2x4 micro-tile, conflict-free staging.
// ---------------------------------------------------------------------------
__global__ __launch_bounds__(256) void k_av(float* __restrict__ ws) {
    const int i0 = blockIdx.x * 32, s0 = blockIdx.y * 64, head = blockIdx.z;
    const float* A = ws + OFF_SC + head * 589824;
    const float* V = ws + OFF_QKV + 2 * 786432 + head * 196608;
    float* O = ws + OFF_ATT + head * 196608;
    __shared__ __align__(16) float As[64][34];
    __shared__ __align__(16) float Bs[64][68];
    const int tid = threadIdx.x, ty = tid >> 4, tx = tid & 15;
    const int sr = tid & 31, sq = tid >> 5;          // staging map
    float acc[2][4] = {};

    for (int dc = 0; dc < 768; dc += 64) {
        __syncthreads();
#pragma unroll
        for (int it = 0; it < 2; it++) {
            int k4 = sq * 4 + 32 * it;
            float4 a = *(const float4*)&A[(i0 + sr) * 768 + dc + k4];
            As[k4 + 0][sr] = a.x; As[k4 + 1][sr] = a.y;
            As[k4 + 2][sr] = a.z; As[k4 + 3][sr] = a.w;
        }
        for (int idx = tid; idx < 1024; idx += 256) {
            int r = idx >> 4, k4 = (idx & 15) * 4;
            *(float4*)&Bs[r][k4] = *(const float4*)&V[(dc + r) * 256 + s0 + k4];
        }
        __syncthreads();
#pragma unroll
        for (int k = 0; k < 64; k++) {
            float a0 = As[k][ty * 2], a1 = As[k][ty * 2 + 1];
            float4 b = *(float4*)&Bs[k][tx * 4];
            acc[0][0] = fmaf(a0, b.x, acc[0][0]); acc[0][1] = fmaf(a0, b.y, acc[0][1]);
            acc[0][2] = fmaf(a0, b.z, acc[0][2]); acc[0][3] = fmaf(a0, b.w, acc[0][3]);
            acc[1][0] = fmaf(a1, b.x, acc[1][0]); acc[1][1] = fmaf(a1, b.y, acc[1][1]);
            acc[1][2] = fmaf(a1, b.z, acc[1][2]); acc[1][3] = fmaf(a1, b.w, acc[1][3]);
        }
    }
#pragma unroll
    for (int e = 0; e < 2; e++) {
        float4 r = make_float4(acc[e][0], acc[e][1], acc[e][2], acc[e][3]);
        *(float4*)&O[(i0 + ty * 2 + e) * 256 + s0 + tx * 4] = r;
    }
}

// ---------------------------------------------------------------------------
// k_ffn: fused pointwise(3->12) + dwconv3x3 + gelu-gate + pointwise(6->3)
// + residual, f32 store. 32x16 pixel tiles (512 blocks), 34x18 halo in LDS.
// ---------------------------------------------------------------------------
struct FfnPtrs { const float* p[6]; };  // pi_w, pi_b, dw_w, dw_b, po_w, po_b

__global__ __launch_bounds__(256) void k_ffn(const float* __restrict__ ws,
                                             const float* __restrict__ x,
                                             FfnPtrs fp,
                                             float* __restrict__ out) {
    const int x0 = blockIdx.x * 32, y0 = blockIdx.y * 16;
    __shared__ float wsm[192];
    __shared__ float p[12][612];
    const int tid = threadIdx.x;
    if (tid < 36)       wsm[tid] = fp.p[0][tid];          // pi_w (12,3)
    else if (tid < 48)  wsm[tid] = fp.p[1][tid - 36];     // pi_b (12)
    else if (tid < 156) wsm[tid] = fp.p[2][tid - 48];     // dw_w (12,9)
    else if (tid < 168) wsm[tid] = fp.p[3][tid - 156];    // dw_b (12)
    else if (tid < 186) wsm[tid] = fp.p[4][tid - 168];    // po_w (3,6)
    else if (tid < 189) wsm[tid] = fp.p[5][tid - 186];    // po_b (3)
    __syncthreads();

    const float* A = ws + OFF_ATT;
    for (int i = tid; i < 612; i += 256) {
        int py = i / 34, px = i % 34;
        int gy = y0 + py - 1, gx = x0 + px - 1;
        bool in = ((unsigned)gy < 512u) && ((unsigned)gx < 512u);
        float a0 = 0.f, a1 = 0.f, a2 = 0.f;
        if (in) {
            int b = gy * 512 + gx;
            a0 = A[b]; a1 = A[262144 + b]; a2 = A[524288 + b];
        }
#pragma unroll
        for (int j = 0; j < 12; j++) {
            float t = in ? (wsm[36 + j] + wsm[j * 3] * a0 + wsm[j * 3 + 1] * a1
                            + wsm[j * 3 + 2] * a2)
                         : 0.f;
            p[j][i] = t;
        }
    }
    __syncthreads();

#pragma unroll
    for (int it = 0; it < 2; it++) {
        int pl = tid + it * 256;
        int ly = pl >> 5, lx = pl & 31;
        float z[12];
#pragma unroll
        for (int j = 0; j < 12; j++) {
            const float* dw = &wsm[48 + j * 9];
            const float* pr = &p[j][ly * 34 + lx];
            z[j] = wsm[156 + j]
                 + dw[0] * pr[0]  + dw[1] * pr[1]  + dw[2] * pr[2]
                 + dw[3] * pr[34] + dw[4] * pr[35] + dw[5] * pr[36]
                 + dw[6] * pr[68] + dw[7] * pr[69] + dw[8] * pr[70];
        }
        float g[6];
#pragma unroll
        for (int j = 0; j < 6; j++) {
            float xx = z[j];
            g[j] = 0.5f * xx * (1.f + erff(xx * 0.70710678118f)) * z[6 + j];
        }
        int b = (y0 + ly) * 512 + (x0 + lx);
#pragma unroll
        for (int co = 0; co < 3; co++) {
            float r = wsm[186 + co];
#pragma unroll
            for (int j = 0; j < 6; j++) r = fmaf(wsm[168 + co * 6 + j], g[j], r);
            r += x[co * 262144 + b];             // residual
            out[co * 262144 + b] = r;
        }
    }
}

// ---------------------------------------------------------------------------
extern "C" void kernel_launch(void* const* d_in, const int* in_sizes, int n_in,
                              void* d_out, int out_size, void* d_ws, size_t ws_size,
                              hipStream_t stream) {
    float* ws = (float*)d_ws;
    float* out = (float*)d_out;
    const float* x   = (const float*)d_in[0];
    const float* cw  = (const float*)d_in[1];
    const float* cb  = (const float*)d_in[2];
    const float* qw1 = (const float*)d_in[3];
    const float* kw1 = (const float*)d_in[7];
    const float* vw1 = (const float*)d_in[11];
    const float* temp= (const float*)d_in[15];

    MlpPtrs mp;
    mp.b1[0] = (const float*)d_in[4];  mp.w2[0] = (const float*)d_in[5];  mp.b2[0] = (const float*)d_in[6];
    mp.b1[1] = (const float*)d_in[8];  mp.w2[1] = (const float*)d_in[9];  mp.b2[1] = (const float*)d_in[10];
    mp.b1[2] = (const float*)d_in[12]; mp.w2[2] = (const float*)d_in[13]; mp.b2[2] = (const float*)d_in[14];

    FfnPtrs fp;
    for (int i = 0; i < 6; i++) fp.p[i] = (const float*)d_in[16 + i];

    k_prep<<<62, 256, 0, stream>>>(qw1, kw1, vw1, mp, ws);
    k_corr<<<dim3(64, 3, 3), 256, 0, stream>>>(x, qw1, kw1, vw1, ws);
    k_mlp <<<dim3(384, 3), 256, 0, stream>>>(cw, cb, mp, ws);
    k_qk  <<<dim3(12, 12, 4), 256, 0, stream>>>(temp, ws);
    k_soft<<<768, 256, 0, stream>>>(ws);
    k_av  <<<dim3(24, 4, 4), 256, 0, stream>>>(ws);
    k_ffn <<<dim3(16, 32), 256, 0, stream>>>(ws, x, fp, out);
}

// Round 11
// 295.090 us; speedup vs baseline: 1.2004x; 1.0013x over previous
//
#include <hip/hip_runtime.h>
#include <math.h>

// ---------------------------------------------------------------------------
// Restormer block, B=1 DIM=3 NC=512 HEADS=2 -> CT=768, NT=32, HID=6. f32 I/O.
//
// R11: (a) k_mlp was L2-BW-bound (2.34 GB reads = 72% of L2 ceiling): now
// 512-thr blocks stage two 19-row G windows in LDS (58 KB, 2 blocks/CU),
// shared by 4 c-waves x 2 ks-halves -> ~5x less L2 traffic, taps via
// ds_read_b128. (b) Attention in bf16 MFMA: Q,K stored bf16 [head][c][s],
// V stored bf16 transposed [head][s][c] by the k_mlp epilogue; k_qk / k_av
// are LDS-free per-wave 32x32 MFMA GEMMs; k_soft emits bf16 attn in-place.
// ---------------------------------------------------------------------------

__device__ __forceinline__ float sigm(float s) {
    return __builtin_amdgcn_rcpf(1.f + __expf(-s));
}

using bf16x8 = __attribute__((ext_vector_type(8))) short;   // 8 bf16 (4 VGPRs)
using f32x16 = __attribute__((ext_vector_type(16))) float;

__device__ __forceinline__ unsigned short f2bf(float f) {
    union { __bf16 h; unsigned short s; } u;
    u.h = (__bf16)f;                    // HW cvt, RNE
    return u.s;
}

// ---- f32 workspace layout (element offsets) -------------------------------
static constexpr int OFF_G   = 0;         // [3v][515 rows][3ci][32n][4]; rows 0,513,514 zero pad
static constexpr int GSTRIDE = 197760;    // 515*384
static constexpr int OFF_S1  = 593280;    // [3v][32] column sums of w1
static constexpr int OFF_QKV = 593408;    // as ushort: Qb[4][768][256] | Kb[4][768][256] | Vt[4][256][768]
static constexpr int OFF_SC  = 2952704;   // [4head][768][768] f32 scores; attn bf16 in-place (row pitch
                                          //   1536 ushorts); also w2 bf16 B-frag pack before k_qk
static constexpr int OFF_ATT = 5312000;   // [4head][768][256] f32 == (3,512,512) flat
// total 6098432 floats = 24.4 MB

struct MlpPtrs {
    const float* b1[3];
    const float* w2[3];
    const float* b2[3];
};

// ---------------------------------------------------------------------------
// k_prep: zero G pad rows; S1[v][n] = sum_u w1v[u][n]; pack w2 into bf16
// B-fragments at OFF_SC (region is free until k_qk overwrites with scores).
// ---------------------------------------------------------------------------
__global__ __launch_bounds__(256) void k_prep(const float* __restrict__ qw1,
                                              const float* __restrict__ kw1,
                                              const float* __restrict__ vw1,
                                              MlpPtrs mp,
                                              float* __restrict__ ws) {
    int i = blockIdx.x * 256 + threadIdx.x;
    if (i < 3456) {                        // zero G pad rows 0,513,514 per v
        int v = i / 1152, rr = (i % 1152) / 384, col = i % 384;
        int row = (rr == 0) ? 0 : (512 + rr);
        ws[OFF_G + v * GSTRIDE + row * 384 + col] = 0.f;
    } else if (i >= 3584 && i < 9728) {    // S1: 96 waves, shuffle-reduce
        int j = i - 3584;
        int w = j >> 6, lane = j & 63;
        int v = w >> 5, n = w & 31;
        const float* w1p = (v == 0) ? qw1 : ((v == 1) ? kw1 : vw1);
        float s = 0.f;
#pragma unroll
        for (int k = 0; k < 8; k++) s += w1p[(lane + 64 * k) * 32 + n];
#pragma unroll
        for (int off = 32; off > 0; off >>= 1) s += __shfl_xor(s, off);
        if (lane == 0) ws[OFF_S1 + w] = s;
    } else if (i >= 9728 && i < 9728 + 6144) {   // w2 -> bf16 B-fragments
        int j = i - 9728;                  // j = v*2048 + hc*64 + lane
        int v = j >> 11, r = j & 2047;
        int hc = r >> 6, lane = r & 63;
        int o = lane & 31, half = lane >> 5;
        int H = hc * 16 + half * 8;
        const float* w2p = mp.w2[v];
        unsigned int d[4];
#pragma unroll
        for (int t = 0; t < 4; t++) {
            unsigned int lo = f2bf(w2p[(H + 2 * t) * 32 + o]);
            unsigned int hi = f2bf(w2p[(H + 2 * t + 1) * 32 + o]);
            d[t] = (hi << 16) | lo;
        }
        uint4* dst = (uint4*)(ws + OFF_SC);
        dst[j] = make_uint4(d[0], d[1], d[2], d[3]);
    }
}

// ---------------------------------------------------------------------------
// k_corr: G[v][h+1][ci][n][dx] = sum_u x[ci][h][u] * w1v[u+1-dx][n]
// grid (64 hblk, 3 ci, 3 v), block 256 = 8 rows x 32 n. float4 G stores.
// ---------------------------------------------------------------------------
__global__ __launch_bounds__(256) void k_corr(const float* __restrict__ x,
                                              const float* __restrict__ qw1,
                                              const float* __restrict__ kw1,
                                              const float* __restrict__ vw1,
                                              float* __restrict__ ws) {
    const int h0 = blockIdx.x * 8, ci = blockIdx.y, v = blockIdx.z;
    const int tid = threadIdx.x;
    __shared__ __align__(16) float ws1t[32 * 516];

    const float* w1f = (v == 0) ? qw1 : ((v == 1) ? kw1 : vw1);
    for (int i = tid; i < 4096; i += 256) {       // transpose-stage w1
        int n_ = i & 31, u = (i >> 5) * 4;
        float a = w1f[(u + 0) * 32 + n_];
        float b = w1f[(u + 1) * 32 + n_];
        float c = w1f[(u + 2) * 32 + n_];
        float d = w1f[(u + 3) * 32 + n_];
        *(float4*)&ws1t[n_ * 516 + u] = make_float4(a, b, c, d);
    }
    if (tid < 32) *(float4*)&ws1t[tid * 516 + 512] = make_float4(0.f, 0.f, 0.f, 0.f);
    __syncthreads();

    const int hp = tid >> 5, n = tid & 31;
    const float* xrow = x + ci * 262144 + (h0 + hp) * 512;
    float a0 = 0.f, a1 = 0.f, a2 = 0.f, pq = 0.f;
    float4 cq = *(float4*)&ws1t[n * 516];
#pragma unroll 4
    for (int k = 0; k < 128; k++) {
        float4 nq = *(float4*)&ws1t[n * 516 + 4 * k + 4];
        float4 x4 = *(const float4*)&xrow[4 * k];
        a1 = fmaf(x4.x, cq.x, a1); a1 = fmaf(x4.y, cq.y, a1);
        a1 = fmaf(x4.z, cq.z, a1); a1 = fmaf(x4.w, cq.w, a1);
        a0 = fmaf(x4.x, cq.y, a0); a0 = fmaf(x4.y, cq.z, a0);
        a0 = fmaf(x4.z, cq.w, a0); a0 = fmaf(x4.w, nq.x, a0);
        a2 = fmaf(x4.x, pq,   a2); a2 = fmaf(x4.y, cq.x, a2);
        a2 = fmaf(x4.z, cq.y, a2); a2 = fmaf(x4.w, cq.z, a2);
        pq = cq.w; cq = nq;
    }
    float* g = ws + OFF_G + v * GSTRIDE + (h0 + hp + 1) * 384 + ci * 128 + n * 4;
    *(float4*)g = make_float4(a0, a1, a2, 0.f);
}

// ---------------------------------------------------------------------------
// k_mlp: block 512 thr = 4 c-waves x 2 ks (K-halves). Per 16-h chunk the
// ks-group stages its 19-row G window into LDS (both groups concurrently;
// 2 x 29.2 KB), then each wave computes 8 y1 per lane from ds_read taps
// (one-row-ahead prefetch), packs bf16 A-fragment, takes the pre-packed w2
// B-fragment, one mfma_f32_32x32x16_bf16 per chunk. ks=1 acc reduced into
// ks=0 via LDS; epilogue writes Q,K bf16 and V bf16-transposed.
// grid (192, 3).
// ---------------------------------------------------------------------------
__global__ __launch_bounds__(512) void k_mlp(const float* __restrict__ cwp,
                                             const float* __restrict__ cbp,
                                             MlpPtrs mp, float* __restrict__ ws) {
    const int v = blockIdx.y;
    const int tid = threadIdx.x;
    const int wv = tid >> 6, lane = tid & 63;
    const int cl = wv >> 1, ks = wv & 1;
    const int c = blockIdx.x * 4 + cl;
    const int n = lane & 31;               // A-row (n-dim) AND B-col (o)
    const int half = lane >> 5;
    __shared__ __align__(16) float gs[2][19 * 384];   // 58.4 KB

    const float* gv = ws + OFF_G + v * GSTRIDE;
    const uint4* w2pk = (const uint4*)(ws + OFF_SC) + (size_t)v * 2048 + lane;
    const int gi = cl * 64 + lane;         // 0..255 within ks-group

    float cwr[3][9];                       // [dy][ci*3+dx]
#pragma unroll
    for (int dy = 0; dy < 3; dy++)
#pragma unroll
        for (int q = 0; q < 9; q++)
            cwr[dy][q] = cwp[c * 27 + (q / 3) * 9 + dy * 3 + (q % 3)];
    const float base = mp.b1[v][n] + cbp[c] * ws[OFF_S1 + v * 32 + n];

    f32x16 acc;
#pragma unroll
    for (int r = 0; r < 16; r++) acc[r] = 0.f;

    for (int hcl = 0; hcl < 16; hcl++) {
        const int hc = ks * 16 + hcl;
        __syncthreads();
        {   // stage rows hc*16 .. hc*16+18 (1824 float4), coalesced
            const float* src = gv + hc * 16 * 384;
            for (int t = gi; t < 1824; t += 256)
                *(float4*)&gs[ks][t * 4] = *(const float4*)(src + t * 4);
        }
        __syncthreads();

        union { uint4 u; bf16x8 b; } bw;
        bw.u = w2pk[hc * 64];              // B fragment (pre-packed bf16)

        const float* wb = &gs[ks][(half * 8) * 384 + n * 4];
        float R[4][9];
#pragma unroll
        for (int s = 0; s < 3; s++) {      // preload local rows 0,1,2
            float4 t0 = *(const float4*)(wb + s * 384);
            float4 t1 = *(const float4*)(wb + s * 384 + 128);
            float4 t2 = *(const float4*)(wb + s * 384 + 256);
            R[s][0] = t0.x; R[s][1] = t0.y; R[s][2] = t0.z;
            R[s][3] = t1.x; R[s][4] = t1.y; R[s][5] = t1.z;
            R[s][6] = t2.x; R[s][7] = t2.y; R[s][8] = t2.z;
        }

        bf16x8 af;
#pragma unroll
        for (int j = 0; j < 8; j++) {
            if (j < 7) {                   // prefetch local row j+3 into slot (j+3)&3
                float4 t0 = *(const float4*)(wb + (j + 3) * 384);
                float4 t1 = *(const float4*)(wb + (j + 3) * 384 + 128);
                float4 t2 = *(const float4*)(wb + (j + 3) * 384 + 256);
                int s = (j + 3) & 3;
                R[s][0] = t0.x; R[s][1] = t0.y; R[s][2] = t0.z;
                R[s][3] = t1.x; R[s][4] = t1.y; R[s][5] = t1.z;
                R[s][6] = t2.x; R[s][7] = t2.y; R[s][8] = t2.z;
            }
            float s0 = base, s1 = 0.f, s2 = 0.f;
#pragma unroll
            for (int q = 0; q < 9; q++) {
                s0 = fmaf(cwr[0][q], R[(j + 0) & 3][q], s0);
                s1 = fmaf(cwr[1][q], R[(j + 1) & 3][q], s1);
                s2 = fmaf(cwr[2][q], R[(j + 2) & 3][q], s2);
            }
            af[j] = (short)f2bf(sigm((s0 + s1) + s2));
        }
        acc = __builtin_amdgcn_mfma_f32_32x32x16_bf16(af, bw.b, acc, 0, 0, 0);
    }

    __syncthreads();
    if (ks == 1) {                          // reduce into ks=0 (reuse gs[0])
#pragma unroll
        for (int r = 0; r < 16; r++) gs[0][cl * 1024 + r * 64 + lane] = acc[r];
    }
    __syncthreads();
    if (ks == 0) {
        const float b2v = mp.b2[v][n];      // o == lane&31
        unsigned short* uq = (unsigned short*)(ws + OFF_QKV);
#pragma unroll
        for (int r = 0; r < 16; r++) {
            float a = acc[r] + gs[0][cl * 1024 + r * 64 + lane];
            int nn = (r & 3) + 8 * (r >> 2) + 4 * half;   // n-dim (row)
            float m = sigm(a + b2v);
            int head = ((n & 1) << 1) | (nn & 1);
            int sidx = ((n >> 1) << 4) | (nn >> 1);
            if (v < 2)  uq[v * 786432 + head * 196608 + c * 256 + sidx] = f2bf(m);
            else        uq[2 * 786432 + head * 196608 + sidx * 768 + c] = f2bf(m);
        }
    }
}

// ---------------------------------------------------------------------------
// k_qk: scores = temp * Q @ K^T (768x768, K=256) per head, bf16 MFMA.
// One wave per 32x32 tile, fragments straight from L2 (no LDS, no barriers).
// grid (24, 6, 4) x 256 thr (4 waves = 4 j-tiles).
// ---------------------------------------------------------------------------
__global__ __launch_bounds__(256) void k_qk(const float* __restrict__ tempr,
                                            float* __restrict__ ws) {
    const unsigned short* uq = (const unsigned short*)(ws + OFF_QKV);
    const int head = blockIdx.z;
    const int wv = threadIdx.x >> 6, lane = threadIdx.x & 63;
    const int i0 = blockIdx.x * 32, j0 = (blockIdx.y * 4 + wv) * 32;
    const int m = lane & 31, half = lane >> 5;

    const unsigned short* Qp = uq + head * 196608 + (i0 + m) * 256 + half * 8;
    const unsigned short* Kp = uq + 786432 + head * 196608 + (j0 + m) * 256 + half * 8;

    f32x16 acc;
#pragma unroll
    for (int r = 0; r < 16; r++) acc[r] = 0.f;
#pragma unroll
    for (int kk = 0; kk < 16; kk++) {
        bf16x8 af = *(const bf16x8*)(Qp + kk * 16);
        bf16x8 bf = *(const bf16x8*)(Kp + kk * 16);
        acc = __builtin_amdgcn_mfma_f32_32x32x16_bf16(af, bf, acc, 0, 0, 0);
    }
    const float temp = tempr[head];
    float* S = ws + OFF_SC + head * 589824;
#pragma unroll
    for (int r = 0; r < 16; r++) {
        int row = (r & 3) + 8 * (r >> 2) + 4 * half;
        S[(i0 + row) * 768 + j0 + m] = acc[r] * temp;
    }
}

// ---------------------------------------------------------------------------
// k_soft: row softmax over 768 (f32 in), emits bf16 attn IN-PLACE (first 768
// ushorts of each 3072-B row slot). 256-thr blocks, 4 rows/block.
// ---------------------------------------------------------------------------
__global__ __launch_bounds__(256) void k_soft(float* __restrict__ ws) {
    float* row = ws + OFF_SC + ((size_t)blockIdx.x * 4 + (threadIdx.x >> 6)) * 768;
    const int t = threadIdx.x & 63;
    float4 v0 = *(float4*)&row[t * 12];
    float4 v1 = *(float4*)&row[t * 12 + 4];
    float4 v2 = *(float4*)&row[t * 12 + 8];
    float m0 = fmaxf(fmaxf(v0.x, v0.y), fmaxf(v0.z, v0.w));
    float m1 = fmaxf(fmaxf(v1.x, v1.y), fmaxf(v1.z, v1.w));
    float m2 = fmaxf(fmaxf(v2.x, v2.y), fmaxf(v2.z, v2.w));
    float m = fmaxf(fmaxf(m0, m1), m2);
#pragma unroll
    for (int off = 32; off > 0; off >>= 1) m = fmaxf(m, __shfl_xor(m, off));
    v0.x = __expf(v0.x - m); v0.y = __expf(v0.y - m); v0.z = __expf(v0.z - m); v0.w = __expf(v0.w - m);
    v1.x = __expf(v1.x - m); v1.y = __expf(v1.y - m); v1.z = __expf(v1.z - m); v1.w = __expf(v1.w - m);
    v2.x = __expf(v2.x - m); v2.y = __expf(v2.y - m); v2.z = __expf(v2.z - m); v2.w = __expf(v2.w - m);
    float s = v0.x + v0.y + v0.z + v0.w + v1.x + v1.y + v1.z + v1.w + v2.x + v2.y + v2.z + v2.w;
#pragma unroll
    for (int off = 32; off > 0; off >>= 1) s += __shfl_xor(s, off);
    float inv = __builtin_amdgcn_rcpf(s);
    unsigned short* rowU = (unsigned short*)row;
    ushort4 w0 = make_ushort4(f2bf(v0.x * inv), f2bf(v0.y * inv), f2bf(v0.z * inv), f2bf(v0.w * inv));
    ushort4 w1 = make_ushort4(f2bf(v1.x * inv), f2bf(v1.y * inv), f2bf(v1.z * inv), f2bf(v1.w * inv));
    ushort4 w2 = make_ushort4(f2bf(v2.x * inv), f2bf(v2.y * inv), f2bf(v2.z * inv), f2bf(v2.w * inv));
    *(ushort4*)&rowU[t * 12]     = w0;
    *(ushort4*)&rowU[t * 12 + 4] = w1;
    *(ushort4*)&rowU[t * 12 + 8] = w2;
}

// ---------------------------------------------------------------------------
// k_av: ATT = attn @ V (768x256, K=768) per head, bf16 MFMA. attn bf16 rows
// (pitch 1536 ushorts), V^T bf16 rows. One wave per 32x32 tile, no LDS.
// grid (24, 2, 4) x 256 thr.
// ---------------------------------------------------------------------------
__global__ __launch_bounds__(256) void k_av(float* __restrict__ ws) {
    const unsigned short* uq = (const unsigned short*)(ws + OFF_QKV);
    const unsigned short* attnU = (const unsigned short*)(ws + OFF_SC);
    const int head = blockIdx.z;
    const int wv = threadIdx.x >> 6, lane = threadIdx.x & 63;
    const int i0 = blockIdx.x * 32, s0 = (blockIdx.y * 4 + wv) * 32;
    const int m = lane & 31, half = lane >> 5;

    const unsigned short* Ap = attnU + (size_t)head * 1179648 + (i0 + m) * 1536 + half * 8;
    const unsigned short* Vp = uq + 2 * 786432 + head * 196608 + (s0 + m) * 768 + half * 8;

    f32x16 acc;
#pragma unroll
    for (int r = 0; r < 16; r++) acc[r] = 0.f;
#pragma unroll
    for (int kk = 0; kk < 48; kk++) {
        bf16x8 af = *(const bf16x8*)(Ap + kk * 16);
        bf16x8 bf = *(const bf16x8*)(Vp + kk * 16);
        acc = __builtin_amdgcn_mfma_f32_32x32x16_bf16(af, bf, acc, 0, 0, 0);
    }
    float* O = ws + OFF_ATT + head * 196608;
#pragma unroll
    for (int r = 0; r < 16; r++) {
        int row = (r & 3) + 8 * (r >> 2) + 4 * half;
        O[(i0 + row) * 256 + s0 + m] = acc[r];
    }
}

// ---------------------------------------------------------------------------
// k_ffn: fused pointwise(3->12) + dwconv3x3 + gelu-gate + pointwise(6->3)
// + residual, f32 store. 32x16 pixel tiles (512 blocks), 34x18 halo in LDS.
// ---------------------------------------------------------------------------
struct FfnPtrs { const float* p[6]; };  // pi_w, pi_b, dw_w, dw_b, po_w, po_b

__global__ __launch_bounds__(256) void k_ffn(const float* __restrict__ ws,
                                             const float* __restrict__ x,
                                             FfnPtrs fp,
                                             float* __restrict__ out) {
    const int x0 = blockIdx.x * 32, y0 = blockIdx.y * 16;
    __shared__ float wsm[192];
    __shared__ float p[12][612];
    const int tid = threadIdx.x;
    if (tid < 36)       wsm[tid] = fp.p[0][tid];          // pi_w (12,3)
    else if (tid < 48)  wsm[tid] = fp.p[1][tid - 36];     // pi_b (12)
    else if (tid < 156) wsm[tid] = fp.p[2][tid - 48];     // dw_w (12,9)
    else if (tid < 168) wsm[tid] = fp.p[3][tid - 156];    // dw_b (12)
    else if (tid < 186) wsm[tid] = fp.p[4][tid - 168];    // po_w (3,6)
    else if (tid < 189) wsm[tid] = fp.p[5][tid - 186];    // po_b (3)
    __syncthreads();

    const float* A = ws + OFF_ATT;
    for (int i = tid; i < 612; i += 256) {
        int py = i / 34, px = i % 34;
        int gy = y0 + py - 1, gx = x0 + px - 1;
        bool in = ((unsigned)gy < 512u) && ((unsigned)gx < 512u);
        float a0 = 0.f, a1 = 0.f, a2 = 0.f;
        if (in) {
            int b = gy * 512 + gx;
            a0 = A[b]; a1 = A[262144 + b]; a2 = A[524288 + b];
        }
#pragma unroll
        for (int j = 0; j < 12; j++) {
            float t = in ? (wsm[36 + j] + wsm[j * 3] * a0 + wsm[j * 3 + 1] * a1
                            + wsm[j * 3 + 2] * a2)
                         : 0.f;
            p[j][i] = t;
        }
    }
    __syncthreads();

#pragma unroll
    for (int it = 0; it < 2; it++) {
        int pl = tid + it * 256;
        int ly = pl >> 5, lx = pl & 31;
        float z[12];
#pragma unroll
        for (int j = 0; j < 12; j++) {
            const float* dw = &wsm[48 + j * 9];
            const float* pr = &p[j][ly * 34 + lx];
            z[j] = wsm[156 + j]
                 + dw[0] * pr[0]  + dw[1] * pr[1]  + dw[2] * pr[2]
                 + dw[3] * pr[34] + dw[4] * pr[35] + dw[5] * pr[36]
                 + dw[6] * pr[68] + dw[7] * pr[69] + dw[8] * pr[70];
        }
        float g[6];
#pragma unroll
        for (int j = 0; j < 6; j++) {
            float xx = z[j];
            g[j] = 0.5f * xx * (1.f + erff(xx * 0.70710678118f)) * z[6 + j];
        }
        int b = (y0 + ly) * 512 + (x0 + lx);
#pragma unroll
        for (int co = 0; co < 3; co++) {
            float r = wsm[186 + co];
#pragma unroll
            for (int j = 0; j < 6; j++) r = fmaf(wsm[168 + co * 6 + j], g[j], r);
            r += x[co * 262144 + b];             // residual
            out[co * 262144 + b] = r;
        }
    }
}

// ---------------------------------------------------------------------------
extern "C" void kernel_launch(void* const* d_in, const int* in_sizes, int n_in,
                              void* d_out, int out_size, void* d_ws, size_t ws_size,
                              hipStream_t stream) {
    float* ws = (float*)d_ws;
    float* out = (float*)d_out;
    const float* x   = (const float*)d_in[0];
    const float* cw  = (const float*)d_in[1];
    const float* cb  = (const float*)d_in[2];
    const float* qw1 = (const float*)d_in[3];
    const float* kw1 = (const float*)d_in[7];
    const float* vw1 = (const float*)d_in[11];
    const float* temp= (const float*)d_in[15];

    MlpPtrs mp;
    mp.b1[0] = (const float*)d_in[4];  mp.w2[0] = (const float*)d_in[5];  mp.b2[0] = (const float*)d_in[6];
    mp.b1[1] = (const float*)d_in[8];  mp.w2[1] = (const float*)d_in[9];  mp.b2[1] = (const float*)d_in[10];
    mp.b1[2] = (const float*)d_in[12]; mp.w2[2] = (const float*)d_in[13]; mp.b2[2] = (const float*)d_in[14];

    FfnPtrs fp;
    for (int i = 0; i < 6; i++) fp.p[i] = (const float*)d_in[16 + i];

    k_prep<<<62, 256, 0, stream>>>(qw1, kw1, vw1, mp, ws);
    k_corr<<<dim3(64, 3, 3), 256, 0, stream>>>(x, qw1, kw1, vw1, ws);
    k_mlp <<<dim3(192, 3), 512, 0, stream>>>(cw, cb, mp, ws);
    k_qk  <<<dim3(24, 6, 4), 256, 0, stream>>>(temp, ws);
    k_soft<<<768, 256, 0, stream>>>(ws);
    k_av  <<<dim3(24, 2, 4), 256, 0, stream>>>(ws);
    k_ffn <<<dim3(16, 32), 256, 0, stream>>>(ws, x, fp, out);
}

// Round 12
// 229.051 us; speedup vs baseline: 1.5464x; 1.2883x over previous
//
#include <hip/hip_runtime.h>
#include <math.h>

// ---------------------------------------------------------------------------
// Restormer block, B=1 DIM=3 NC=512 HEADS=2 -> CT=768, NT=32, HID=6. f32 I/O.
//
// R12: k_mlp = R10's no-LDS rolling-register structure (R11's in-loop LDS
// staging regressed: barrier-drain + 2 blocks/CU), but each wave now computes
// TWO c channels off the same G tap reads (B-fragment w2 is c-independent)
// -> L2 read traffic halves (2.34 -> 1.17 GB, the measured binding resource).
// 4-way K-split per c-pair (block 256 = 4 ks-waves), LDS only for the final
// accumulator reduction. Attention stays R11: bf16 MFMA k_qk/k_av (no LDS),
// k_soft emits bf16 in-place, k_mlp epilogue writes bf16 Q,K and V^T.
// ---------------------------------------------------------------------------

__device__ __forceinline__ float sigm(float s) {
    return __builtin_amdgcn_rcpf(1.f + __expf(-s));
}

using bf16x8 = __attribute__((ext_vector_type(8))) short;   // 8 bf16 (4 VGPRs)
using f32x16 = __attribute__((ext_vector_type(16))) float;

__device__ __forceinline__ unsigned short f2bf(float f) {
    union { __bf16 h; unsigned short s; } u;
    u.h = (__bf16)f;                    // HW cvt, RNE
    return u.s;
}

// ---- f32 workspace layout (element offsets) -------------------------------
static constexpr int OFF_G   = 0;         // [3v][515 rows][3ci][32n][4]; rows 0,513,514 zero pad
static constexpr int GSTRIDE = 197760;    // 515*384
static constexpr int OFF_S1  = 593280;    // [3v][32] column sums of w1
static constexpr int OFF_QKV = 593408;    // as ushort: Qb[4][768][256] | Kb[4][768][256] | Vt[4][256][768]
static constexpr int OFF_SC  = 2952704;   // [4head][768][768] f32 scores; attn bf16 in-place (row pitch
                                          //   1536 ushorts); also w2 bf16 B-frag pack before k_qk
static constexpr int OFF_ATT = 5312000;   // [4head][768][256] f32 == (3,512,512) flat
// total 6098432 floats = 24.4 MB

struct MlpPtrs {
    const float* b1[3];
    const float* w2[3];
    const float* b2[3];
};

// ---------------------------------------------------------------------------
// k_prep: zero G pad rows; S1[v][n] = sum_u w1v[u][n]; pack w2 into bf16
// B-fragments at OFF_SC (region is free until k_qk overwrites with scores).
// ---------------------------------------------------------------------------
__global__ __launch_bounds__(256) void k_prep(const float* __restrict__ qw1,
                                              const float* __restrict__ kw1,
                                              const float* __restrict__ vw1,
                                              MlpPtrs mp,
                                              float* __restrict__ ws) {
    int i = blockIdx.x * 256 + threadIdx.x;
    if (i < 3456) {                        // zero G pad rows 0,513,514 per v
        int v = i / 1152, rr = (i % 1152) / 384, col = i % 384;
        int row = (rr == 0) ? 0 : (512 + rr);
        ws[OFF_G + v * GSTRIDE + row * 384 + col] = 0.f;
    } else if (i >= 3584 && i < 9728) {    // S1: 96 waves, shuffle-reduce
        int j = i - 3584;
        int w = j >> 6, lane = j & 63;
        int v = w >> 5, n = w & 31;
        const float* w1p = (v == 0) ? qw1 : ((v == 1) ? kw1 : vw1);
        float s = 0.f;
#pragma unroll
        for (int k = 0; k < 8; k++) s += w1p[(lane + 64 * k) * 32 + n];
#pragma unroll
        for (int off = 32; off > 0; off >>= 1) s += __shfl_xor(s, off);
        if (lane == 0) ws[OFF_S1 + w] = s;
    } else if (i >= 9728 && i < 9728 + 6144) {   // w2 -> bf16 B-fragments
        int j = i - 9728;                  // j = v*2048 + hc*64 + lane
        int v = j >> 11, r = j & 2047;
        int hc = r >> 6, lane = r & 63;
        int o = lane & 31, half = lane >> 5;
        int H = hc * 16 + half * 8;
        const float* w2p = mp.w2[v];
        unsigned int d[4];
#pragma unroll
        for (int t = 0; t < 4; t++) {
            unsigned int lo = f2bf(w2p[(H + 2 * t) * 32 + o]);
            unsigned int hi = f2bf(w2p[(H + 2 * t + 1) * 32 + o]);
            d[t] = (hi << 16) | lo;
        }
        uint4* dst = (uint4*)(ws + OFF_SC);
        dst[j] = make_uint4(d[0], d[1], d[2], d[3]);
    }
}

// ---------------------------------------------------------------------------
// k_corr: G[v][h+1][ci][n][dx] = sum_u x[ci][h][u] * w1v[u+1-dx][n]
// grid (64 hblk, 3 ci, 3 v), block 256 = 8 rows x 32 n. float4 G stores.
// ---------------------------------------------------------------------------
__global__ __launch_bounds__(256) void k_corr(const float* __restrict__ x,
                                              const float* __restrict__ qw1,
                                              const float* __restrict__ kw1,
                                              const float* __restrict__ vw1,
                                              float* __restrict__ ws) {
    const int h0 = blockIdx.x * 8, ci = blockIdx.y, v = blockIdx.z;
    const int tid = threadIdx.x;
    __shared__ __align__(16) float ws1t[32 * 516];

    const float* w1f = (v == 0) ? qw1 : ((v == 1) ? kw1 : vw1);
    for (int i = tid; i < 4096; i += 256) {       // transpose-stage w1
        int n_ = i & 31, u = (i >> 5) * 4;
        float a = w1f[(u + 0) * 32 + n_];
        float b = w1f[(u + 1) * 32 + n_];
        float c = w1f[(u + 2) * 32 + n_];
        float d = w1f[(u + 3) * 32 + n_];
        *(float4*)&ws1t[n_ * 516 + u] = make_float4(a, b, c, d);
    }
    if (tid < 32) *(float4*)&ws1t[tid * 516 + 512] = make_float4(0.f, 0.f, 0.f, 0.f);
    __syncthreads();

    const int hp = tid >> 5, n = tid & 31;
    const float* xrow = x + ci * 262144 + (h0 + hp) * 512;
    float a0 = 0.f, a1 = 0.f, a2 = 0.f, pq = 0.f;
    float4 cq = *(float4*)&ws1t[n * 516];
#pragma unroll 4
    for (int k = 0; k < 128; k++) {
        float4 nq = *(float4*)&ws1t[n * 516 + 4 * k + 4];
        float4 x4 = *(const float4*)&xrow[4 * k];
        a1 = fmaf(x4.x, cq.x, a1); a1 = fmaf(x4.y, cq.y, a1);
        a1 = fmaf(x4.z, cq.z, a1); a1 = fmaf(x4.w, cq.w, a1);
        a0 = fmaf(x4.x, cq.y, a0); a0 = fmaf(x4.y, cq.z, a0);
        a0 = fmaf(x4.z, cq.w, a0); a0 = fmaf(x4.w, nq.x, a0);
        a2 = fmaf(x4.x, pq,   a2); a2 = fmaf(x4.y, cq.x, a2);
        a2 = fmaf(x4.z, cq.y, a2); a2 = fmaf(x4.w, cq.z, a2);
        pq = cq.w; cq = nq;
    }
    float* g = ws + OFF_G + v * GSTRIDE + (h0 + hp + 1) * 384 + ci * 128 + n * 4;
    *(float4*)g = make_float4(a0, a1, a2, 0.f);
}

// ---------------------------------------------------------------------------
// k_mlp: block 256 thr = 4 ks-waves, all working on the same c-pair
// (c0 = 2*bx, c1 = c0+1). Per 16-h chunk (8 chunks per wave): rolling 4-slot
// register rows (31 float4 loads, shared by both c's), per j: 2x 27-tap FMA
// + sigmoid -> two bf16 A-fragments; one shared pre-packed w2 B-fragment;
// two mfma_f32_32x32x16_bf16. ks=1..3 accs reduced into ks=0 via 24 KB LDS
// (single barrier, outside the loop). Epilogue writes bf16 Q,K and V^T.
// grid (384, 3) = 1152 blocks, 4608 waves.
// ---------------------------------------------------------------------------
__global__ __launch_bounds__(256) void k_mlp(const float* __restrict__ cwp,
                                             const float* __restrict__ cbp,
                                             MlpPtrs mp, float* __restrict__ ws) {
    const int v = blockIdx.y;
    const int tid = threadIdx.x;
    const int ks = tid >> 6, lane = tid & 63;
    const int c0 = blockIdx.x * 2, c1 = c0 + 1;
    const int n = lane & 31;               // A-row (n-dim) AND B-col (o)
    const int half = lane >> 5;
    __shared__ float red[3][2][16][64];    // 24 KB: ks 1..3 -> epilogue wave

    const float* gv = ws + OFF_G + v * GSTRIDE;
    const uint4* w2pk = (const uint4*)(ws + OFF_SC) + (size_t)v * 2048 + lane;

    float cwr0[3][9], cwr1[3][9];          // [dy][ci*3+dx]
#pragma unroll
    for (int dy = 0; dy < 3; dy++)
#pragma unroll
        for (int q = 0; q < 9; q++) {
            cwr0[dy][q] = cwp[c0 * 27 + (q / 3) * 9 + dy * 3 + (q % 3)];
            cwr1[dy][q] = cwp[c1 * 27 + (q / 3) * 9 + dy * 3 + (q % 3)];
        }
    const float s1v = ws[OFF_S1 + v * 32 + n];
    const float b1v = mp.b1[v][n];
    const float base0 = b1v + cbp[c0] * s1v;
    const float base1 = b1v + cbp[c1] * s1v;

    f32x16 acc0, acc1;
#pragma unroll
    for (int r = 0; r < 16; r++) { acc0[r] = 0.f; acc1[r] = 0.f; }

    for (int hcl = 0; hcl < 8; hcl++) {
        const int hc = ks * 8 + hcl;
        const int H = hc * 16 + half * 8;          // this lane's first h
        const float* rp = gv + H * 384 + n * 4;

        union { uint4 u; bf16x8 b; } bw;           // shared B fragment
        bw.u = w2pk[hc * 64];

        float R[4][9];                             // rolling tap rows
#pragma unroll
        for (int s = 0; s < 4; s++) {
            float4 t0 = *(const float4*)(rp + s * 384);
            float4 t1 = *(const float4*)(rp + s * 384 + 128);
            float4 t2 = *(const float4*)(rp + s * 384 + 256);
            R[s][0] = t0.x; R[s][1] = t0.y; R[s][2] = t0.z;
            R[s][3] = t1.x; R[s][4] = t1.y; R[s][5] = t1.z;
            R[s][6] = t2.x; R[s][7] = t2.y; R[s][8] = t2.z;
        }

        bf16x8 af0, af1;
#pragma unroll
        for (int j = 0; j < 8; j++) {
            float a0 = base0, a1 = 0.f, a2 = 0.f;
            float b0 = base1, b1 = 0.f, b2 = 0.f;
#pragma unroll
            for (int q = 0; q < 9; q++) {
                float r0 = R[(j + 0) & 3][q], r1 = R[(j + 1) & 3][q], r2 = R[(j + 2) & 3][q];
                a0 = fmaf(cwr0[0][q], r0, a0);
                a1 = fmaf(cwr0[1][q], r1, a1);
                a2 = fmaf(cwr0[2][q], r2, a2);
                b0 = fmaf(cwr1[0][q], r0, b0);
                b1 = fmaf(cwr1[1][q], r1, b1);
                b2 = fmaf(cwr1[2][q], r2, b2);
            }
            if (j < 6) {                   // refill slot j&3 with row H+j+4 (<=513)
                const float* q4 = rp + (j + 4) * 384;
                float4 t0 = *(const float4*)(q4);
                float4 t1 = *(const float4*)(q4 + 128);
                float4 t2 = *(const float4*)(q4 + 256);
                int s = (j + 3) & 3 == 0 ? (j & 3) : (j & 3);   // slot j&3
                R[j & 3][0] = t0.x; R[j & 3][1] = t0.y; R[j & 3][2] = t0.z;
                R[j & 3][3] = t1.x; R[j & 3][4] = t1.y; R[j & 3][5] = t1.z;
                R[j & 3][6] = t2.x; R[j & 3][7] = t2.y; R[j & 3][8] = t2.z;
            }
            af0[j] = (short)f2bf(sigm((a0 + a1) + a2));
            af1[j] = (short)f2bf(sigm((b0 + b1) + b2));
        }
        acc0 = __builtin_amdgcn_mfma_f32_32x32x16_bf16(af0, bw.b, acc0, 0, 0, 0);
        acc1 = __builtin_amdgcn_mfma_f32_32x32x16_bf16(af1, bw.b, acc1, 0, 0, 0);
    }

    if (ks > 0) {
#pragma unroll
        for (int r = 0; r < 16; r++) {
            red[ks - 1][0][r][lane] = acc0[r];
            red[ks - 1][1][r][lane] = acc1[r];
        }
    }
    __syncthreads();
    if (ks == 0) {
        const float b2v = mp.b2[v][n];      // o == lane&31
        unsigned short* uq = (unsigned short*)(ws + OFF_QKV);
#pragma unroll
        for (int cc = 0; cc < 2; cc++) {
            const int c = c0 + cc;
#pragma unroll
            for (int r = 0; r < 16; r++) {
                float a = (cc == 0 ? acc0[r] : acc1[r])
                        + red[0][cc][r][lane] + red[1][cc][r][lane] + red[2][cc][r][lane];
                int nn = (r & 3) + 8 * (r >> 2) + 4 * half;   // n-dim (row)
                float m = sigm(a + b2v);
                int head = ((n & 1) << 1) | (nn & 1);
                int sidx = ((n >> 1) << 4) | (nn >> 1);
                if (v < 2)  uq[v * 786432 + head * 196608 + c * 256 + sidx] = f2bf(m);
                else        uq[2 * 786432 + head * 196608 + sidx * 768 + c] = f2bf(m);
            }
        }
    }
}

// ---------------------------------------------------------------------------
// k_qk: scores = temp * Q @ K^T (768x768, K=256) per head, bf16 MFMA.
// One wave per 32x32 tile, fragments straight from L2 (no LDS, no barriers).
// grid (24, 6, 4) x 256 thr (4 waves = 4 j-tiles).
// ---------------------------------------------------------------------------
__global__ __launch_bounds__(256) void k_qk(const float* __restrict__ tempr,
                                            float* __restrict__ ws) {
    const unsigned short* uq = (const unsigned short*)(ws + OFF_QKV);
    const int head = blockIdx.z;
    const int wv = threadIdx.x >> 6, lane = threadIdx.x & 63;
    const int i0 = blockIdx.x * 32, j0 = (blockIdx.y * 4 + wv) * 32;
    const int m = lane & 31, half = lane >> 5;

    const unsigned short* Qp = uq + head * 196608 + (i0 + m) * 256 + half * 8;
    const unsigned short* Kp = uq + 786432 + head * 196608 + (j0 + m) * 256 + half * 8;

    f32x16 acc;
#pragma unroll
    for (int r = 0; r < 16; r++) acc[r] = 0.f;
#pragma unroll
    for (int kk = 0; kk < 16; kk++) {
        bf16x8 af = *(const bf16x8*)(Qp + kk * 16);
        bf16x8 bf = *(const bf16x8*)(Kp + kk * 16);
        acc = __builtin_amdgcn_mfma_f32_32x32x16_bf16(af, bf, acc, 0, 0, 0);
    }
    const float temp = tempr[head];
    float* S = ws + OFF_SC + head * 589824;
#pragma unroll
    for (int r = 0; r < 16; r++) {
        int row = (r & 3) + 8 * (r >> 2) + 4 * half;
        S[(i0 + row) * 768 + j0 + m] = acc[r] * temp;
    }
}

// ---------------------------------------------------------------------------
// k_soft: row softmax over 768 (f32 in), emits bf16 attn IN-PLACE (first 768
// ushorts of each 3072-B row slot). 256-thr blocks, 4 rows/block.
// ---------------------------------------------------------------------------
__global__ __launch_bounds__(256) void k_soft(float* __restrict__ ws) {
    float* row = ws + OFF_SC + ((size_t)blockIdx.x * 4 + (threadIdx.x >> 6)) * 768;
    const int t = threadIdx.x & 63;
    float4 v0 = *(float4*)&row[t * 12];
    float4 v1 = *(float4*)&row[t * 12 + 4];
    float4 v2 = *(float4*)&row[t * 12 + 8];
    float m0 = fmaxf(fmaxf(v0.x, v0.y), fmaxf(v0.z, v0.w));
    float m1 = fmaxf(fmaxf(v1.x, v1.y), fmaxf(v1.z, v1.w));
    float m2 = fmaxf(fmaxf(v2.x, v2.y), fmaxf(v2.z, v2.w));
    float m = fmaxf(fmaxf(m0, m1), m2);
#pragma unroll
    for (int off = 32; off > 0; off >>= 1) m = fmaxf(m, __shfl_xor(m, off));
    v0.x = __expf(v0.x - m); v0.y = __expf(v0.y - m); v0.z = __expf(v0.z - m); v0.w = __expf(v0.w - m);
    v1.x = __expf(v1.x - m); v1.y = __expf(v1.y - m); v1.z = __expf(v1.z - m); v1.w = __expf(v1.w - m);
    v2.x = __expf(v2.x - m); v2.y = __expf(v2.y - m); v2.z = __expf(v2.z - m); v2.w = __expf(v2.w - m);
    float s = v0.x + v0.y + v0.z + v0.w + v1.x + v1.y + v1.z + v1.w + v2.x + v2.y + v2.z + v2.w;
#pragma unroll
    for (int off = 32; off > 0; off >>= 1) s += __shfl_xor(s, off);
    float inv = __builtin_amdgcn_rcpf(s);
    unsigned short* rowU = (unsigned short*)row;
    ushort4 w0 = make_ushort4(f2bf(v0.x * inv), f2bf(v0.y * inv), f2bf(v0.z * inv), f2bf(v0.w * inv));
    ushort4 w1 = make_ushort4(f2bf(v1.x * inv), f2bf(v1.y * inv), f2bf(v1.z * inv), f2bf(v1.w * inv));
    ushort4 w2 = make_ushort4(f2bf(v2.x * inv), f2bf(v2.y * inv), f2bf(v2.z * inv), f2bf(v2.w * inv));
    *(ushort4*)&rowU[t * 12]     = w0;
    *(ushort4*)&rowU[t * 12 + 4] = w1;
    *(ushort4*)&rowU[t * 12 + 8] = w2;
}

// ---------------------------------------------------------------------------
// k_av: ATT = attn @ V (768x256, K=768) per head, bf16 MFMA. attn bf16 rows
// (pitch 1536 ushorts), V^T bf16 rows. One wave per 32x32 tile, no LDS.
// grid (24, 2, 4) x 256 thr.
// ---------------------------------------------------------------------------
__global__ __launch_bounds__(256) void k_av(float* __restrict__ ws) {
    const unsigned short* uq = (const unsigned short*)(ws + OFF_QKV);
    const unsigned short* attnU = (const unsigned short*)(ws + OFF_SC);
    const int head = blockIdx.z;
    const int wv = threadIdx.x >> 6, lane = threadIdx.x & 63;
    const int i0 = blockIdx.x * 32, s0 = (blockIdx.y * 4 + wv) * 32;
    const int m = lane & 31, half = lane >> 5;

    const unsigned short* Ap = attnU + (size_t)head * 1179648 + (i0 + m) * 1536 + half * 8;
    const unsigned short* Vp = uq + 2 * 786432 + head * 196608 + (s0 + m) * 768 + half * 8;

    f32x16 acc;
#pragma unroll
    for (int r = 0; r < 16; r++) acc[r] = 0.f;
#pragma unroll
    for (int kk = 0; kk < 48; kk++) {
        bf16x8 af = *(const bf16x8*)(Ap + kk * 16);
        bf16x8 bf = *(const bf16x8*)(Vp + kk * 16);
        acc = __builtin_amdgcn_mfma_f32_32x32x16_bf16(af, bf, acc, 0, 0, 0);
    }
    float* O = ws + OFF_ATT + head * 196608;
#pragma unroll
    for (int r = 0; r < 16; r++) {
        int row = (r & 3) + 8 * (r >> 2) + 4 * half;
        O[(i0 + row) * 256 + s0 + m] = acc[r];
    }
}

// ---------------------------------------------------------------------------
// k_ffn: fused pointwise(3->12) + dwconv3x3 + gelu-gate + pointwise(6->3)
// + residual, f32 store. 32x16 pixel tiles (512 blocks), 34x18 halo in LDS.
// ---------------------------------------------------------------------------
struct FfnPtrs { const float* p[6]; };  // pi_w, pi_b, dw_w, dw_b, po_w, po_b

__global__ __launch_bounds__(256) void k_ffn(const float* __restrict__ ws,
                                             const float* __restrict__ x,
                                             FfnPtrs fp,
                                             float* __restrict__ out) {
    const int x0 = blockIdx.x * 32, y0 = blockIdx.y * 16;
    __shared__ float wsm[192];
    __shared__ float p[12][612];
    const int tid = threadIdx.x;
    if (tid < 36)       wsm[tid] = fp.p[0][tid];          // pi_w (12,3)
    else if (tid < 48)  wsm[tid] = fp.p[1][tid - 36];     // pi_b (12)
    else if (tid < 156) wsm[tid] = fp.p[2][tid - 48];     // dw_w (12,9)
    else if (tid < 168) wsm[tid] = fp.p[3][tid - 156];    // dw_b (12)
    else if (tid < 186) wsm[tid] = fp.p[4][tid - 168];    // po_w (3,6)
    else if (tid < 189) wsm[tid] = fp.p[5][tid - 186];    // po_b (3)
    __syncthreads();

    const float* A = ws + OFF_ATT;
    for (int i = tid; i < 612; i += 256) {
        int py = i / 34, px = i % 34;
        int gy = y0 + py - 1, gx = x0 + px - 1;
        bool in = ((unsigned)gy < 512u) && ((unsigned)gx < 512u);
        float a0 = 0.f, a1 = 0.f, a2 = 0.f;
        if (in) {
            int b = gy * 512 + gx;
            a0 = A[b]; a1 = A[262144 + b]; a2 = A[524288 + b];
        }
#pragma unroll
        for (int j = 0; j < 12; j++) {
            float t = in ? (wsm[36 + j] + wsm[j * 3] * a0 + wsm[j * 3 + 1] * a1
                            + wsm[j * 3 + 2] * a2)
                         : 0.f;
            p[j][i] = t;
        }
    }
    __syncthreads();

#pragma unroll
    for (int it = 0; it < 2; it++) {
        int pl = tid + it * 256;
        int ly = pl >> 5, lx = pl & 31;
        float z[12];
#pragma unroll
        for (int j = 0; j < 12; j++) {
            const float* dw = &wsm[48 + j * 9];
            const float* pr = &p[j][ly * 34 + lx];
            z[j] = wsm[156 + j]
                 + dw[0] * pr[0]  + dw[1] * pr[1]  + dw[2] * pr[2]
                 + dw[3] * pr[34] + dw[4] * pr[35] + dw[5] * pr[36]
                 + dw[6] * pr[68] + dw[7] * pr[69] + dw[8] * pr[70];
        }
        float g[6];
#pragma unroll
        for (int j = 0; j < 6; j++) {
            float xx = z[j];
            g[j] = 0.5f * xx * (1.f + erff(xx * 0.70710678118f)) * z[6 + j];
        }
        int b = (y0 + ly) * 512 + (x0 + lx);
#pragma unroll
        for (int co = 0; co < 3; co++) {
            float r = wsm[186 + co];
#pragma unroll
            for (int j = 0; j < 6; j++) r = fmaf(wsm[168 + co * 6 + j], g[j], r);
            r += x[co * 262144 + b];             // residual
            out[co * 262144 + b] = r;
        }
    }
}

// ---------------------------------------------------------------------------
extern "C" void kernel_launch(void* const* d_in, const int* in_sizes, int n_in,
                              void* d_out, int out_size, void* d_ws, size_t ws_size,
                              hipStream_t stream) {
    float* ws = (float*)d_ws;
    float* out = (float*)d_out;
    const float* x   = (const float*)d_in[0];
    const float* cw  = (const float*)d_in[1];
    const float* cb  = (const float*)d_in[2];
    const float* qw1 = (const float*)d_in[3];
    const float* kw1 = (const float*)d_in[7];
    const float* vw1 = (const float*)d_in[11];
    const float* temp= (const float*)d_in[15];

    MlpPtrs mp;
    mp.b1[0] = (const float*)d_in[4];  mp.w2[0] = (const float*)d_in[5];  mp.b2[0] = (const float*)d_in[6];
    mp.b1[1] = (const float*)d_in[8];  mp.w2[1] = (const float*)d_in[9];  mp.b2[1] = (const float*)d_in[10];
    mp.b1[2] = (const float*)d_in[12]; mp.w2[2] = (const float*)d_in[13]; mp.b2[2] = (const float*)d_in[14];

    FfnPtrs fp;
    for (int i = 0; i < 6; i++) fp.p[i] = (const float*)d_in[16 + i];

    k_prep<<<62, 256, 0, stream>>>(qw1, kw1, vw1, mp, ws);
    k_corr<<<dim3(64, 3, 3), 256, 0, stream>>>(x, qw1, kw1, vw1, ws);
    k_mlp <<<dim3(384, 3), 256, 0, stream>>>(cw, cb, mp, ws);
    k_qk  <<<dim3(24, 6, 4), 256, 0, stream>>>(temp, ws);
    k_soft<<<768, 256, 0, stream>>>(ws);
    k_av  <<<dim3(24, 2, 4), 256, 0, stream>>>(ws);
    k_ffn <<<dim3(16, 32), 256, 0, stream>>>(ws, x, fp, out);
}

// Round 13
// 228.692 us; speedup vs baseline: 1.5489x; 1.0016x over previous
//
#include <hip/hip_runtime.h>
#include <math.h>

// ---------------------------------------------------------------------------
// Restormer block, B=1 DIM=3 NC=512 HEADS=2 -> CT=768, NT=32, HID=6. f32 I/O.
//
// R13: attention fused into ONE kernel k_attn per (head, 32-row band):
// QK -> scores in registers (3 f32x16/wave x 8 waves) -> block softmax
// (m-lane shuffle reduce + LDS cross-wave max/sum) -> bf16 attn in LDS ->
// PV from LDS A-frags + V^T from L2. Removes k_qk/k_soft/k_av, the f32
// score round-trip (9.4 MB) and the bf16 attn round-trip (4.7 MB).
// k_mlp unchanged from R12 (c-pair sharing, 4-way K-split, w2 pre-pack).
// ---------------------------------------------------------------------------

__device__ __forceinline__ float sigm(float s) {
    return __builtin_amdgcn_rcpf(1.f + __expf(-s));
}

using bf16x8 = __attribute__((ext_vector_type(8))) short;   // 8 bf16 (4 VGPRs)
using f32x16 = __attribute__((ext_vector_type(16))) float;

__device__ __forceinline__ unsigned short f2bf(float f) {
    union { __bf16 h; unsigned short s; } u;
    u.h = (__bf16)f;                    // HW cvt, RNE
    return u.s;
}

// ---- f32 workspace layout (element offsets) -------------------------------
static constexpr int OFF_G   = 0;         // [3v][515 rows][3ci][32n][4]; rows 0,513,514 zero pad
static constexpr int GSTRIDE = 197760;    // 515*384
static constexpr int OFF_S1  = 593280;    // [3v][32] column sums of w1
static constexpr int OFF_QKV = 593408;    // as ushort: Qb[4][768][256] | Kb[4][768][256] | Vt[4][256][768]
static constexpr int OFF_SC  = 2952704;   // w2 bf16 B-frag pack [3v][32hc][64lane][uint4]
static constexpr int OFF_ATT = 5312000;   // [4head][768][256] f32 == (3,512,512) flat
// total 6098432 floats = 24.4 MB

struct MlpPtrs {
    const float* b1[3];
    const float* w2[3];
    const float* b2[3];
};

// ---------------------------------------------------------------------------
// k_prep: zero G pad rows; S1[v][n] = sum_u w1v[u][n]; pack w2 into bf16
// B-fragments at OFF_SC.
// ---------------------------------------------------------------------------
__global__ __launch_bounds__(256) void k_prep(const float* __restrict__ qw1,
                                              const float* __restrict__ kw1,
                                              const float* __restrict__ vw1,
                                              MlpPtrs mp,
                                              float* __restrict__ ws) {
    int i = blockIdx.x * 256 + threadIdx.x;
    if (i < 3456) {                        // zero G pad rows 0,513,514 per v
        int v = i / 1152, rr = (i % 1152) / 384, col = i % 384;
        int row = (rr == 0) ? 0 : (512 + rr);
        ws[OFF_G + v * GSTRIDE + row * 384 + col] = 0.f;
    } else if (i >= 3584 && i < 9728) {    // S1: 96 waves, shuffle-reduce
        int j = i - 3584;
        int w = j >> 6, lane = j & 63;
        int v = w >> 5, n = w & 31;
        const float* w1p = (v == 0) ? qw1 : ((v == 1) ? kw1 : vw1);
        float s = 0.f;
#pragma unroll
        for (int k = 0; k < 8; k++) s += w1p[(lane + 64 * k) * 32 + n];
#pragma unroll
        for (int off = 32; off > 0; off >>= 1) s += __shfl_xor(s, off);
        if (lane == 0) ws[OFF_S1 + w] = s;
    } else if (i >= 9728 && i < 9728 + 6144) {   // w2 -> bf16 B-fragments
        int j = i - 9728;                  // j = v*2048 + hc*64 + lane
        int v = j >> 11, r = j & 2047;
        int hc = r >> 6, lane = r & 63;
        int o = lane & 31, half = lane >> 5;
        int H = hc * 16 + half * 8;
        const float* w2p = mp.w2[v];
        unsigned int d[4];
#pragma unroll
        for (int t = 0; t < 4; t++) {
            unsigned int lo = f2bf(w2p[(H + 2 * t) * 32 + o]);
            unsigned int hi = f2bf(w2p[(H + 2 * t + 1) * 32 + o]);
            d[t] = (hi << 16) | lo;
        }
        uint4* dst = (uint4*)(ws + OFF_SC);
        dst[j] = make_uint4(d[0], d[1], d[2], d[3]);
    }
}

// ---------------------------------------------------------------------------
// k_corr: G[v][h+1][ci][n][dx] = sum_u x[ci][h][u] * w1v[u+1-dx][n]
// grid (64 hblk, 3 ci, 3 v), block 256 = 8 rows x 32 n. float4 G stores.
// ---------------------------------------------------------------------------
__global__ __launch_bounds__(256) void k_corr(const float* __restrict__ x,
                                              const float* __restrict__ qw1,
                                              const float* __restrict__ kw1,
                                              const float* __restrict__ vw1,
                                              float* __restrict__ ws) {
    const int h0 = blockIdx.x * 8, ci = blockIdx.y, v = blockIdx.z;
    const int tid = threadIdx.x;
    __shared__ __align__(16) float ws1t[32 * 516];

    const float* w1f = (v == 0) ? qw1 : ((v == 1) ? kw1 : vw1);
    for (int i = tid; i < 4096; i += 256) {       // transpose-stage w1
        int n_ = i & 31, u = (i >> 5) * 4;
        float a = w1f[(u + 0) * 32 + n_];
        float b = w1f[(u + 1) * 32 + n_];
        float c = w1f[(u + 2) * 32 + n_];
        float d = w1f[(u + 3) * 32 + n_];
        *(float4*)&ws1t[n_ * 516 + u] = make_float4(a, b, c, d);
    }
    if (tid < 32) *(float4*)&ws1t[tid * 516 + 512] = make_float4(0.f, 0.f, 0.f, 0.f);
    __syncthreads();

    const int hp = tid >> 5, n = tid & 31;
    const float* xrow = x + ci * 262144 + (h0 + hp) * 512;
    float a0 = 0.f, a1 = 0.f, a2 = 0.f, pq = 0.f;
    float4 cq = *(float4*)&ws1t[n * 516];
#pragma unroll 4
    for (int k = 0; k < 128; k++) {
        float4 nq = *(float4*)&ws1t[n * 516 + 4 * k + 4];
        float4 x4 = *(const float4*)&xrow[4 * k];
        a1 = fmaf(x4.x, cq.x, a1); a1 = fmaf(x4.y, cq.y, a1);
        a1 = fmaf(x4.z, cq.z, a1); a1 = fmaf(x4.w, cq.w, a1);
        a0 = fmaf(x4.x, cq.y, a0); a0 = fmaf(x4.y, cq.z, a0);
        a0 = fmaf(x4.z, cq.w, a0); a0 = fmaf(x4.w, nq.x, a0);
        a2 = fmaf(x4.x, pq,   a2); a2 = fmaf(x4.y, cq.x, a2);
        a2 = fmaf(x4.z, cq.y, a2); a2 = fmaf(x4.w, cq.z, a2);
        pq = cq.w; cq = nq;
    }
    float* g = ws + OFF_G + v * GSTRIDE + (h0 + hp + 1) * 384 + ci * 128 + n * 4;
    *(float4*)g = make_float4(a0, a1, a2, 0.f);
}

// ---------------------------------------------------------------------------
// k_mlp: block 256 thr = 4 ks-waves, same c-pair. Rolling register tap rows
// shared by 2 c's, pre-packed w2 B-fragments, 2 MFMAs per chunk. LDS only
// for the final reduction. Epilogue writes bf16 Q,K and V^T. (R12, proven.)
// ---------------------------------------------------------------------------
__global__ __launch_bounds__(256) void k_mlp(const float* __restrict__ cwp,
                                             const float* __restrict__ cbp,
                                             MlpPtrs mp, float* __restrict__ ws) {
    const int v = blockIdx.y;
    const int tid = threadIdx.x;
    const int ks = tid >> 6, lane = tid & 63;
    const int c0 = blockIdx.x * 2, c1 = c0 + 1;
    const int n = lane & 31;               // A-row (n-dim) AND B-col (o)
    const int half = lane >> 5;
    __shared__ float red[3][2][16][64];    // 24 KB: ks 1..3 -> epilogue wave

    const float* gv = ws + OFF_G + v * GSTRIDE;
    const uint4* w2pk = (const uint4*)(ws + OFF_SC) + (size_t)v * 2048 + lane;

    float cwr0[3][9], cwr1[3][9];          // [dy][ci*3+dx]
#pragma unroll
    for (int dy = 0; dy < 3; dy++)
#pragma unroll
        for (int q = 0; q < 9; q++) {
            cwr0[dy][q] = cwp[c0 * 27 + (q / 3) * 9 + dy * 3 + (q % 3)];
            cwr1[dy][q] = cwp[c1 * 27 + (q / 3) * 9 + dy * 3 + (q % 3)];
        }
    const float s1v = ws[OFF_S1 + v * 32 + n];
    const float b1v = mp.b1[v][n];
    const float base0 = b1v + cbp[c0] * s1v;
    const float base1 = b1v + cbp[c1] * s1v;

    f32x16 acc0, acc1;
#pragma unroll
    for (int r = 0; r < 16; r++) { acc0[r] = 0.f; acc1[r] = 0.f; }

    for (int hcl = 0; hcl < 8; hcl++) {
        const int hc = ks * 8 + hcl;
        const int H = hc * 16 + half * 8;          // this lane's first h
        const float* rp = gv + H * 384 + n * 4;

        union { uint4 u; bf16x8 b; } bw;           // shared B fragment
        bw.u = w2pk[hc * 64];

        float R[4][9];                             // rolling tap rows
#pragma unroll
        for (int s = 0; s < 4; s++) {
            float4 t0 = *(const float4*)(rp + s * 384);
            float4 t1 = *(const float4*)(rp + s * 384 + 128);
            float4 t2 = *(const float4*)(rp + s * 384 + 256);
            R[s][0] = t0.x; R[s][1] = t0.y; R[s][2] = t0.z;
            R[s][3] = t1.x; R[s][4] = t1.y; R[s][5] = t1.z;
            R[s][6] = t2.x; R[s][7] = t2.y; R[s][8] = t2.z;
        }

        bf16x8 af0, af1;
#pragma unroll
        for (int j = 0; j < 8; j++) {
            float a0 = base0, a1 = 0.f, a2 = 0.f;
            float b0 = base1, b1 = 0.f, b2 = 0.f;
#pragma unroll
            for (int q = 0; q < 9; q++) {
                float r0 = R[(j + 0) & 3][q], r1 = R[(j + 1) & 3][q], r2 = R[(j + 2) & 3][q];
                a0 = fmaf(cwr0[0][q], r0, a0);
                a1 = fmaf(cwr0[1][q], r1, a1);
                a2 = fmaf(cwr0[2][q], r2, a2);
                b0 = fmaf(cwr1[0][q], r0, b0);
                b1 = fmaf(cwr1[1][q], r1, b1);
                b2 = fmaf(cwr1[2][q], r2, b2);
            }
            if (j < 6) {                   // refill slot j&3 with row H+j+4 (<=513)
                const float* q4 = rp + (j + 4) * 384;
                float4 t0 = *(const float4*)(q4);
                float4 t1 = *(const float4*)(q4 + 128);
                float4 t2 = *(const float4*)(q4 + 256);
                R[j & 3][0] = t0.x; R[j & 3][1] = t0.y; R[j & 3][2] = t0.z;
                R[j & 3][3] = t1.x; R[j & 3][4] = t1.y; R[j & 3][5] = t1.z;
                R[j & 3][6] = t2.x; R[j & 3][7] = t2.y; R[j & 3][8] = t2.z;
            }
            af0[j] = (short)f2bf(sigm((a0 + a1) + a2));
            af1[j] = (short)f2bf(sigm((b0 + b1) + b2));
        }
        acc0 = __builtin_amdgcn_mfma_f32_32x32x16_bf16(af0, bw.b, acc0, 0, 0, 0);
        acc1 = __builtin_amdgcn_mfma_f32_32x32x16_bf16(af1, bw.b, acc1, 0, 0, 0);
    }

    if (ks > 0) {
#pragma unroll
        for (int r = 0; r < 16; r++) {
            red[ks - 1][0][r][lane] = acc0[r];
            red[ks - 1][1][r][lane] = acc1[r];
        }
    }
    __syncthreads();
    if (ks == 0) {
        const float b2v = mp.b2[v][n];      // o == lane&31
        unsigned short* uq = (unsigned short*)(ws + OFF_QKV);
#pragma unroll
        for (int cc = 0; cc < 2; cc++) {
            const int c = c0 + cc;
#pragma unroll
            for (int r = 0; r < 16; r++) {
                float a = (cc == 0 ? acc0[r] : acc1[r])
                        + red[0][cc][r][lane] + red[1][cc][r][lane] + red[2][cc][r][lane];
                int nn = (r & 3) + 8 * (r >> 2) + 4 * half;   // n-dim (row)
                float m = sigm(a + b2v);
                int head = ((n & 1) << 1) | (nn & 1);
                int sidx = ((n >> 1) << 4) | (nn >> 1);
                if (v < 2)  uq[v * 786432 + head * 196608 + c * 256 + sidx] = f2bf(m);
                else        uq[2 * 786432 + head * 196608 + sidx * 768 + c] = f2bf(m);
            }
        }
    }
}

// ---------------------------------------------------------------------------
// k_attn: fused QK^T * temp -> softmax -> @V for one (head, 32-row band).
// Block 512 = 8 waves. Phase 1: wave w computes j-tiles w*3..w*3+2 (scores
// in 3 f32x16 regs). Phase 2: block softmax — m-lane shuffle reduce, tiny
// LDS cross-wave max/sum. Phase 3: attn bf16 -> LDS (pitch 776), wave w
// computes output s-tile w via MFMA with A-frags from LDS, V^T from L2.
// grid (24 iband, 4 head).
// ---------------------------------------------------------------------------
__global__ __launch_bounds__(512) void k_attn(const float* __restrict__ tempr,
                                              float* __restrict__ ws) {
    const unsigned short* uq = (const unsigned short*)(ws + OFF_QKV);
    const int head = blockIdx.y;
    const int i0 = blockIdx.x * 32;
    const int w = threadIdx.x >> 6, lane = threadIdx.x & 63;
    const int m = lane & 31, half = lane >> 5;

    __shared__ __align__(16) unsigned short ap[32][776];   // attn bf16, padded
    __shared__ float mxw[8][32];
    __shared__ float smw[8][32];
    __shared__ float gmx[32];
    __shared__ float gsm[32];

    const float temp = tempr[head];
    const unsigned short* Qp = uq + head * 196608 + (i0 + m) * 256 + half * 8;

    // ---- phase 1: QK^T for 3 j-tiles --------------------------------------
    f32x16 acc[3];
#pragma unroll
    for (int t = 0; t < 3; t++)
#pragma unroll
        for (int r = 0; r < 16; r++) acc[t][r] = 0.f;
#pragma unroll
    for (int t = 0; t < 3; t++) {
        const int j0 = (w * 3 + t) * 32;
        const unsigned short* Kp = uq + 786432 + head * 196608 + (j0 + m) * 256 + half * 8;
#pragma unroll
        for (int kk = 0; kk < 16; kk++) {
            bf16x8 af = *(const bf16x8*)(Qp + kk * 16);
            bf16x8 bf = *(const bf16x8*)(Kp + kk * 16);
            acc[t] = __builtin_amdgcn_mfma_f32_32x32x16_bf16(af, bf, acc[t], 0, 0, 0);
        }
    }
    // scale by temperature (before max: temp sign matters in general)
#pragma unroll
    for (int t = 0; t < 3; t++)
#pragma unroll
        for (int r = 0; r < 16; r++) acc[t][r] *= temp;

    // ---- phase 2: block softmax -------------------------------------------
    int rowv[16];
#pragma unroll
    for (int r = 0; r < 16; r++) rowv[r] = (r & 3) + 8 * (r >> 2) + 4 * half;

    float rmx[16];
#pragma unroll
    for (int r = 0; r < 16; r++)
        rmx[r] = fmaxf(fmaxf(acc[0][r], acc[1][r]), acc[2][r]);
#pragma unroll
    for (int off = 16; off > 0; off >>= 1)
#pragma unroll
        for (int r = 0; r < 16; r++) rmx[r] = fmaxf(rmx[r], __shfl_xor(rmx[r], off));
    if (m == 0) {
#pragma unroll
        for (int r = 0; r < 16; r++) mxw[w][rowv[r]] = rmx[r];
    }
    __syncthreads();
    if (threadIdx.x < 32) {
        float g = mxw[0][threadIdx.x];
#pragma unroll
        for (int ww = 1; ww < 8; ww++) g = fmaxf(g, mxw[ww][threadIdx.x]);
        gmx[threadIdx.x] = g;
    }
    __syncthreads();

    float rsm[16];
#pragma unroll
    for (int r = 0; r < 16; r++) {
        float gm = gmx[rowv[r]];
        float e0 = __expf(acc[0][r] - gm);
        float e1 = __expf(acc[1][r] - gm);
        float e2 = __expf(acc[2][r] - gm);
        acc[0][r] = e0; acc[1][r] = e1; acc[2][r] = e2;
        rsm[r] = (e0 + e1) + e2;
    }
#pragma unroll
    for (int off = 16; off > 0; off >>= 1)
#pragma unroll
        for (int r = 0; r < 16; r++) rsm[r] += __shfl_xor(rsm[r], off);
    if (m == 0) {
#pragma unroll
        for (int r = 0; r < 16; r++) smw[w][rowv[r]] = rsm[r];
    }
    __syncthreads();
    if (threadIdx.x < 32) {
        float g = smw[0][threadIdx.x];
#pragma unroll
        for (int ww = 1; ww < 8; ww++) g += smw[ww][threadIdx.x];
        gsm[threadIdx.x] = g;
    }
    __syncthreads();

    // ---- phase 3: attn bf16 -> LDS, then PV --------------------------------
#pragma unroll
    for (int r = 0; r < 16; r++) {
        float inv = __builtin_amdgcn_rcpf(gsm[rowv[r]]);
#pragma unroll
        for (int t = 0; t < 3; t++)
            ap[rowv[r]][(w * 3 + t) * 32 + m] = f2bf(acc[t][r] * inv);
    }
    __syncthreads();

    const int s0 = w * 32;
    const unsigned short* Vp = uq + 2 * 786432 + head * 196608 + (s0 + m) * 768 + half * 8;
    f32x16 po;
#pragma unroll
    for (int r = 0; r < 16; r++) po[r] = 0.f;
#pragma unroll
    for (int kk = 0; kk < 48; kk++) {
        bf16x8 af = *(const bf16x8*)&ap[m][half * 8 + kk * 16];
        bf16x8 bf = *(const bf16x8*)(Vp + kk * 16);
        po = __builtin_amdgcn_mfma_f32_32x32x16_bf16(af, bf, po, 0, 0, 0);
    }
    float* O = ws + OFF_ATT + head * 196608;
#pragma unroll
    for (int r = 0; r < 16; r++) {
        O[(i0 + rowv[r]) * 256 + s0 + m] = po[r];
    }
}

// ---------------------------------------------------------------------------
// k_ffn: fused pointwise(3->12) + dwconv3x3 + gelu-gate + pointwise(6->3)
// + residual, f32 store. 32x16 pixel tiles (512 blocks), 34x18 halo in LDS.
// ---------------------------------------------------------------------------
struct FfnPtrs { const float* p[6]; };  // pi_w, pi_b, dw_w, dw_b, po_w, po_b

__global__ __launch_bounds__(256) void k_ffn(const float* __restrict__ ws,
                                             const float* __restrict__ x,
                                             FfnPtrs fp,
                                             float* __restrict__ out) {
    const int x0 = blockIdx.x * 32, y0 = blockIdx.y * 16;
    __shared__ float wsm[192];
    __shared__ float p[12][612];
    const int tid = threadIdx.x;
    if (tid < 36)       wsm[tid] = fp.p[0][tid];          // pi_w (12,3)
    else if (tid < 48)  wsm[tid] = fp.p[1][tid - 36];     // pi_b (12)
    else if (tid < 156) wsm[tid] = fp.p[2][tid - 48];     // dw_w (12,9)
    else if (tid < 168) wsm[tid] = fp.p[3][tid - 156];    // dw_b (12)
    else if (tid < 186) wsm[tid] = fp.p[4][tid - 168];    // po_w (3,6)
    else if (tid < 189) wsm[tid] = fp.p[5][tid - 186];    // po_b (3)
    __syncthreads();

    const float* A = ws + OFF_ATT;
    for (int i = tid; i < 612; i += 256) {
        int py = i / 34, px = i % 34;
        int gy = y0 + py - 1, gx = x0 + px - 1;
        bool in = ((unsigned)gy < 512u) && ((unsigned)gx < 512u);
        float a0 = 0.f, a1 = 0.f, a2 = 0.f;
        if (in) {
            int b = gy * 512 + gx;
            a0 = A[b]; a1 = A[262144 + b]; a2 = A[524288 + b];
        }
#pragma unroll
        for (int j = 0; j < 12; j++) {
            float t = in ? (wsm[36 + j] + wsm[j * 3] * a0 + wsm[j * 3 + 1] * a1
                            + wsm[j * 3 + 2] * a2)
                         : 0.f;
            p[j][i] = t;
        }
    }
    __syncthreads();

#pragma unroll
    for (int it = 0; it < 2; it++) {
        int pl = tid + it * 256;
        int ly = pl >> 5, lx = pl & 31;
        float z[12];
#pragma unroll
        for (int j = 0; j < 12; j++) {
            const float* dw = &wsm[48 + j * 9];
            const float* pr = &p[j][ly * 34 + lx];
            z[j] = wsm[156 + j]
                 + dw[0] * pr[0]  + dw[1] * pr[1]  + dw[2] * pr[2]
                 + dw[3] * pr[34] + dw[4] * pr[35] + dw[5] * pr[36]
                 + dw[6] * pr[68] + dw[7] * pr[69] + dw[8] * pr[70];
        }
        float g[6];
#pragma unroll
        for (int j = 0; j < 6; j++) {
            float xx = z[j];
            g[j] = 0.5f * xx * (1.f + erff(xx * 0.70710678118f)) * z[6 + j];
        }
        int b = (y0 + ly) * 512 + (x0 + lx);
#pragma unroll
        for (int co = 0; co < 3; co++) {
            float r = wsm[186 + co];
#pragma unroll
            for (int j = 0; j < 6; j++) r = fmaf(wsm[168 + co * 6 + j], g[j], r);
            r += x[co * 262144 + b];             // residual
            out[co * 262144 + b] = r;
        }
    }
}

// ---------------------------------------------------------------------------
extern "C" void kernel_launch(void* const* d_in, const int* in_sizes, int n_in,
                              void* d_out, int out_size, void* d_ws, size_t ws_size,
                              hipStream_t stream) {
    float* ws = (float*)d_ws;
    float* out = (float*)d_out;
    const float* x   = (const float*)d_in[0];
    const float* cw  = (const float*)d_in[1];
    const float* cb  = (const float*)d_in[2];
    const float* qw1 = (const float*)d_in[3];
    const float* kw1 = (const float*)d_in[7];
    const float* vw1 = (const float*)d_in[11];
    const float* temp= (const float*)d_in[15];

    MlpPtrs mp;
    mp.b1[0] = (const float*)d_in[4];  mp.w2[0] = (const float*)d_in[5];  mp.b2[0] = (const float*)d_in[6];
    mp.b1[1] = (const float*)d_in[8];  mp.w2[1] = (const float*)d_in[9];  mp.b2[1] = (const float*)d_in[10];
    mp.b1[2] = (const float*)d_in[12]; mp.w2[2] = (const float*)d_in[13]; mp.b2[2] = (const float*)d_in[14];

    FfnPtrs fp;
    for (int i = 0; i < 6; i++) fp.p[i] = (const float*)d_in[16 + i];

    k_prep<<<62, 256, 0, stream>>>(qw1, kw1, vw1, mp, ws);
    k_corr<<<dim3(64, 3, 3), 256, 0, stream>>>(x, qw1, kw1, vw1, ws);
    k_mlp <<<dim3(384, 3), 256, 0, stream>>>(cw, cb, mp, ws);
    k_attn<<<dim3(24, 4), 512, 0, stream>>>(temp, ws);
    k_ffn <<<dim3(16, 32), 256, 0, stream>>>(ws, x, fp, out);
}